// Round 1
// baseline (1010.357 us; speedup 1.0000x reference)
//
#include <hip/hip_runtime.h>
#include <hip/hip_bf16.h>
#include <math.h>

// Restormer-style channel attention, f32 baseline.
// B=4, C=192, H=W=128, HEADS=4, ch=48, HW=16384.
//
// Pipeline:
//  k0: transpose w_qkv -> wqT[c][o]  (uniform s_load-friendly)
//  for g in {q,k,v}:
//    k1: conv1x1 slab  y1[b][192][HW]   (GEMM, 64-acc per thread)
//    k2: dwconv3x3     -> q_ws / k_ws / d_out(v)
//  k3: S = q k^T partials + sum-of-squares partials (fixed-order reduce)
//  k4: reduce partials, norms, softmax, fold into MT = (w_proj . blockdiag(attn))^T
//  k5: out = MT @ v   (in-place over d_out: column transform, 192-acc)
//
// ws usage: 38,621,184 floats = 154.5 MB.

#define B_ 4
#define C_ 192
#define H_ 128
#define W_ 128
#define HW_ 16384
#define HEADS_ 4
#define CH_ 48

// ws offsets (floats)
#define OFF_WQT  0u            // 192*576      = 110592
#define OFF_MT   110592u       // 4*192*192    = 147456
#define OFF_SP   258048u       // 4*4*16*2400  = 614400
#define OFF_Y1   872448u       // 4*192*16384  = 12582912
#define OFF_Q    13455360u     // 12582912
#define OFF_K    26038272u     // 12582912  -> total 38621184 floats

__global__ void k0_transpose(const float* __restrict__ wq, float* __restrict__ wqT) {
    int idx = blockIdx.x * 256 + threadIdx.x;
    if (idx < 576 * 192) {
        int o = idx / 192, c = idx % 192;
        wqT[c * 576 + o] = wq[idx];
    }
}

// conv1x1: y1[b][oc0+o][p] = sum_c x[b][c][p] * wqT[c][g*192+oc0+o]
__global__ __launch_bounds__(256, 4) void k1_conv1x1(
    const float* __restrict__ x, const float* __restrict__ wqT,
    float* __restrict__ y1, int g) {
    int t = threadIdx.x;
    int p = blockIdx.x * 256 + t;
    int oc0 = blockIdx.y * 64;
    int b = blockIdx.z;
    const float* xb = x + (size_t)b * C_ * HW_ + p;
    float acc[64];
#pragma unroll
    for (int o = 0; o < 64; ++o) acc[o] = 0.f;
    float xv = xb[0];
    for (int c = 0; c < C_; ++c) {
        float xn = (c + 1 < C_) ? xb[(size_t)(c + 1) * HW_] : 0.f;
        const float* wrow = wqT + c * 576 + g * 192 + oc0;  // wave-uniform -> s_load
#pragma unroll
        for (int o = 0; o < 64; ++o) acc[o] = fmaf(xv, wrow[o], acc[o]);
        xv = xn;
    }
    float* yb = y1 + ((size_t)b * C_ + oc0) * HW_ + p;
#pragma unroll
    for (int o = 0; o < 64; ++o) yb[(size_t)o * HW_] = acc[o];
}

// depthwise 3x3, zero pad. dst = q_ws (g=0), k_ws (g=1), d_out (g=2, holds v)
__global__ __launch_bounds__(512, 2) void k2_dwconv(
    const float* __restrict__ y1, const float* __restrict__ wdw,
    float* __restrict__ dst, int g) {
    int t = threadIdx.x;
    int c = blockIdx.y, b = blockIdx.z;
    int row = blockIdx.x * 4 + (t >> 7);
    int col = t & 127;
    const float* yp = y1 + ((size_t)b * C_ + c) * HW_;
    const float* wd = wdw + (size_t)(g * C_ + c) * 9;  // uniform -> s_load
    float w00 = wd[0], w01 = wd[1], w02 = wd[2];
    float w10 = wd[3], w11 = wd[4], w12 = wd[5];
    float w20 = wd[6], w21 = wd[7], w22 = wd[8];
    int rm = row - 1, rp = row + 1, cm = col - 1, cp = col + 1;
    bool rmv = rm >= 0, rpv = rp < H_, cmv = cm >= 0, cpv = cp < W_;
    const float* r0 = yp + (size_t)rm * W_;
    const float* r1 = yp + (size_t)row * W_;
    const float* r2 = yp + (size_t)rp * W_;
    float s = 0.f;
    if (rmv) {
        if (cmv) s = fmaf(w00, r0[cm], s);
        s = fmaf(w01, r0[col], s);
        if (cpv) s = fmaf(w02, r0[cp], s);
    }
    if (cmv) s = fmaf(w10, r1[cm], s);
    s = fmaf(w11, r1[col], s);
    if (cpv) s = fmaf(w12, r1[cp], s);
    if (rpv) {
        if (cmv) s = fmaf(w20, r2[cm], s);
        s = fmaf(w21, r2[col], s);
        if (cpv) s = fmaf(w22, r2[cp], s);
    }
    dst[((size_t)b * C_ + c) * HW_ + (size_t)row * W_ + col] = s;
}

// S-GEMM partials: per (b,h,chunk of 1024 px): S[48][48] + qss[48] + kss[48]
// Fixed-order reductions (deterministic): per-lane over j-subset, then 4-wave
// LDS tree, then k4 sums 16 chunk partials.
__global__ __launch_bounds__(256, 2) void k3_qk(
    const float* __restrict__ qb, const float* __restrict__ kb,
    float* __restrict__ Sp) {
    __shared__ float qs[48 * 66];
    __shared__ float ks[48 * 66];
    __shared__ float sred[4 * 2304];
    __shared__ float sredN[4 * 96];
    int t = threadIdx.x;
    int chunk = blockIdx.x, h = blockIdx.y, b = blockIdx.z;
    int w = t >> 6, l = t & 63;
    int ci = (l & 7) * 6, di = (l >> 3) * 6;
    const float* qrow = qb + ((size_t)b * C_ + h * CH_) * HW_;
    const float* krow = kb + ((size_t)b * C_ + h * CH_) * HW_;
    float S[6][6];
#pragma unroll
    for (int uc = 0; uc < 6; ++uc)
#pragma unroll
        for (int ud = 0; ud < 6; ++ud) S[uc][ud] = 0.f;
    float qss[6] = {0, 0, 0, 0, 0, 0}, kss[6] = {0, 0, 0, 0, 0, 0};

    for (int s = 0; s < 16; ++s) {
        __syncthreads();
        int base = chunk * 1024 + s * 64;
        for (int idx = t; idx < 48 * 64; idx += 256) {
            int c = idx >> 6, j = idx & 63;
            qs[c * 66 + j] = qrow[(size_t)c * HW_ + base + j];
            ks[c * 66 + j] = krow[(size_t)c * HW_ + base + j];
        }
        __syncthreads();
        for (int jo = 0; jo < 16; ++jo) {
            int jj = w * 16 + jo;
            float rq[6], rk[6];
#pragma unroll
            for (int u = 0; u < 6; ++u) {
                rq[u] = qs[(ci + u) * 66 + jj];
                rk[u] = ks[(di + u) * 66 + jj];
            }
#pragma unroll
            for (int uc = 0; uc < 6; ++uc)
#pragma unroll
                for (int ud = 0; ud < 6; ++ud)
                    S[uc][ud] = fmaf(rq[uc], rk[ud], S[uc][ud]);
            if (l < 8) {  // di==0 lanes: their ci covers all 48 channels
#pragma unroll
                for (int u = 0; u < 6; ++u) qss[u] = fmaf(rq[u], rq[u], qss[u]);
            }
            if ((l & 7) == 0) {  // ci==0 lanes: their di covers all 48
#pragma unroll
                for (int u = 0; u < 6; ++u) kss[u] = fmaf(rk[u], rk[u], kss[u]);
            }
        }
    }
#pragma unroll
    for (int uc = 0; uc < 6; ++uc)
#pragma unroll
        for (int ud = 0; ud < 6; ++ud)
            sred[w * 2304 + (ci + uc) * 48 + (di + ud)] = S[uc][ud];
    if (l < 8) {
#pragma unroll
        for (int u = 0; u < 6; ++u) sredN[w * 96 + ci + u] = qss[u];
    }
    if ((l & 7) == 0) {
#pragma unroll
        for (int u = 0; u < 6; ++u) sredN[w * 96 + 48 + di + u] = kss[u];
    }
    __syncthreads();
    size_t ob = ((size_t)(b * HEADS_ + h) * 16 + chunk) * 2400;
    for (int idx = t; idx < 2304; idx += 256) {
        Sp[ob + idx] = (sred[idx] + sred[2304 + idx]) +
                       (sred[4608 + idx] + sred[6912 + idx]);
    }
    if (t < 96) {
        Sp[ob + 2304 + t] = (sredN[t] + sredN[96 + t]) +
                            (sredN[192 + t] + sredN[288 + t]);
    }
}

// reduce chunk partials -> norms -> softmax -> MT[cg][o] = sum_c wp[o][h*48+c]*A[c][d]
__global__ __launch_bounds__(256, 2) void k4_softmax(
    const float* __restrict__ Sp, const float* __restrict__ wp,
    const float* __restrict__ temp, float* __restrict__ MT) {
    __shared__ float sS[2304];
    __shared__ float sN[96];
    int t = threadIdx.x;
    int bh = blockIdx.x;
    int b = bh >> 2, h = bh & 3;
    size_t base = (size_t)bh * 16 * 2400;
    for (int idx = t; idx < 2400; idx += 256) {
        float v = 0.f;
        for (int ch = 0; ch < 16; ++ch) v += Sp[base + (size_t)ch * 2400 + idx];
        if (idx < 2304) sS[idx] = v; else sN[idx - 2304] = v;
    }
    __syncthreads();
    if (t < 96) sN[t] = fmaxf(sqrtf(fmaxf(sN[t], 0.f)), 1e-12f);
    __syncthreads();
    if (t < 48) {
        float tv = temp[h];
        float qn = sN[t];
        float L[48];
        float m = -1e30f;
#pragma unroll
        for (int d = 0; d < 48; ++d) {
            float xv = sS[t * 48 + d] * tv / (qn * sN[48 + d]);
            L[d] = xv;
            m = fmaxf(m, xv);
        }
        float sum = 0.f;
#pragma unroll
        for (int d = 0; d < 48; ++d) {
            float e = expf(L[d] - m);
            L[d] = e;
            sum += e;
        }
        float inv = 1.f / sum;
#pragma unroll
        for (int d = 0; d < 48; ++d) sS[t * 48 + d] = L[d] * inv;
    }
    __syncthreads();
    for (int idx = t; idx < 48 * 192; idx += 256) {
        int d = idx / 192, o = idx % 192;
        const float* wpo = wp + (size_t)o * C_ + h * CH_;
        float sum = 0.f;
#pragma unroll
        for (int c = 0; c < 48; ++c) sum = fmaf(wpo[c], sS[c * 48 + d], sum);
        MT[(size_t)b * C_ * C_ + (size_t)(h * CH_ + d) * C_ + o] = sum;
    }
}

// out = MT^T-applied GEMM over v, in place over d_out.
// Each thread owns one pixel column: reads v[0..191][p] then writes out[0..191][p].
__global__ __launch_bounds__(256, 2) void k5_out(
    const float* __restrict__ MT, float* dout) {
    int t = threadIdx.x;
    int p = blockIdx.x * 256 + t;
    int b = blockIdx.y;
    const float* MTb = MT + (size_t)b * C_ * C_;
    float* db = dout + (size_t)b * C_ * HW_;
    float acc[192];
#pragma unroll
    for (int o = 0; o < 192; ++o) acc[o] = 0.f;
    float vv = db[p];
    for (int c = 0; c < C_; ++c) {
        float vn = (c + 1 < C_) ? db[(size_t)(c + 1) * HW_ + p] : 0.f;
        const float* mrow = MTb + c * C_;  // uniform -> s_load
#pragma unroll
        for (int o = 0; o < 192; ++o) acc[o] = fmaf(vv, mrow[o], acc[o]);
        vv = vn;
    }
#pragma unroll
    for (int o = 0; o < 192; ++o) db[(size_t)o * HW_ + p] = acc[o];
}

extern "C" void kernel_launch(void* const* d_in, const int* in_sizes, int n_in,
                              void* d_out, int out_size, void* d_ws, size_t ws_size,
                              hipStream_t stream) {
    const float* x     = (const float*)d_in[0];
    const float* wqkv  = (const float*)d_in[1];
    const float* wdw   = (const float*)d_in[2];
    const float* wproj = (const float*)d_in[3];
    const float* temp  = (const float*)d_in[4];
    float* out = (float*)d_out;
    float* ws  = (float*)d_ws;

    float* wqT = ws + OFF_WQT;
    float* MT  = ws + OFF_MT;
    float* Sp  = ws + OFF_SP;
    float* y1  = ws + OFF_Y1;
    float* q   = ws + OFF_Q;
    float* k   = ws + OFF_K;

    hipLaunchKernelGGL(k0_transpose, dim3(432), dim3(256), 0, stream, wqkv, wqT);
    for (int g = 0; g < 3; ++g) {
        hipLaunchKernelGGL(k1_conv1x1, dim3(64, 3, 4), dim3(256), 0, stream,
                           x, wqT, y1, g);
        float* dst = (g == 0) ? q : (g == 1) ? k : out;
        hipLaunchKernelGGL(k2_dwconv, dim3(32, 192, 4), dim3(512), 0, stream,
                           y1, wdw, dst, g);
    }
    hipLaunchKernelGGL(k3_qk, dim3(16, 4, 4), dim3(256), 0, stream, q, k, Sp);
    hipLaunchKernelGGL(k4_softmax, dim3(16), dim3(256), 0, stream, Sp, wproj, temp, MT);
    hipLaunchKernelGGL(k5_out, dim3(64, 4), dim3(256), 0, stream, MT, out);
}

// Round 2
// 788.349 us; speedup vs baseline: 1.2816x; 1.2816x over previous
//
#include <hip/hip_runtime.h>
#include <hip/hip_bf16.h>
#include <math.h>

// Restormer-style channel attention, f32, round 2: occupancy/spill fixes.
// B=4, C=192, H=W=128, HEADS=4, ch=48, HW=16384.
//
// Order: k0; [g0: k1,k2 -> q]; [g1: k1,k2 -> k]; k3(q,k -> Sp in y1 slab);
//        k4(Sp -> MT); [g2: k1,k2 -> v in q slab]; k5(MT,v -> out).
//
// ws usage: 38,006,784 floats = 152.0 MB (Sp aliases y1).

#define B_ 4
#define C_ 192
#define H_ 128
#define W_ 128
#define HW_ 16384
#define HEADS_ 4
#define CH_ 48
#define CHUNKS_ 64          // k3 pixel chunks; 256 px per chunk

// ws offsets (floats)
#define OFF_WQT  0u            // 192*576      = 110592
#define OFF_MT   110592u       // 4*192*192    = 147456 -> ends 258048
#define OFF_Y1   258048u       // 12582912 (Sp aliases the first 2457600)
#define OFF_Q    12840960u     // 12582912
#define OFF_K    25423872u     // 12582912 -> total 38006784

__global__ void k0_transpose(const float* __restrict__ wq, float* __restrict__ wqT) {
    int idx = blockIdx.x * 256 + threadIdx.x;
    if (idx < 576 * 192) {
        int o = idx / 192, c = idx % 192;
        wqT[c * 576 + o] = wq[idx];
    }
}

// conv1x1: y1[b][oc0+o][p] = sum_c x[b][c][p] * wqT[c][g*192+oc0+o]
__global__ __launch_bounds__(256, 4) void k1_conv1x1(
    const float* __restrict__ x, const float* __restrict__ wqT,
    float* __restrict__ y1, int g) {
    int t = threadIdx.x;
    int p = blockIdx.x * 256 + t;
    int oc0 = blockIdx.y * 64;
    int b = blockIdx.z;
    const float* xb = x + (size_t)b * C_ * HW_ + p;
    float acc[64];
#pragma unroll
    for (int o = 0; o < 64; ++o) acc[o] = 0.f;
    float xv = xb[0];
    for (int c = 0; c < C_; ++c) {
        float xn = (c + 1 < C_) ? xb[(size_t)(c + 1) * HW_] : 0.f;
        const float* wrow = wqT + c * 576 + g * 192 + oc0;  // wave-uniform -> s_load
#pragma unroll
        for (int o = 0; o < 64; ++o) acc[o] = fmaf(xv, wrow[o], acc[o]);
        xv = xn;
    }
    float* yb = y1 + ((size_t)b * C_ + oc0) * HW_ + p;
#pragma unroll
    for (int o = 0; o < 64; ++o) yb[(size_t)o * HW_] = acc[o];
}

// depthwise 3x3, zero pad. 256-thread blocks, 2 rows each.
__global__ __launch_bounds__(256, 8) void k2_dwconv(
    const float* __restrict__ y1, const float* __restrict__ wdw,
    float* __restrict__ dst, int g) {
    int t = threadIdx.x;
    int c = blockIdx.y, b = blockIdx.z;
    int row = blockIdx.x * 2 + (t >> 7);
    int col = t & 127;
    const float* yp = y1 + ((size_t)b * C_ + c) * HW_;
    const float* wd = wdw + (size_t)(g * C_ + c) * 9;  // uniform -> s_load
    float w00 = wd[0], w01 = wd[1], w02 = wd[2];
    float w10 = wd[3], w11 = wd[4], w12 = wd[5];
    float w20 = wd[6], w21 = wd[7], w22 = wd[8];
    int rm = row - 1, rp = row + 1, cm = col - 1, cp = col + 1;
    bool rmv = rm >= 0, rpv = rp < H_, cmv = cm >= 0, cpv = cp < W_;
    const float* r0 = yp + (size_t)rm * W_;
    const float* r1 = yp + (size_t)row * W_;
    const float* r2 = yp + (size_t)rp * W_;
    float s = 0.f;
    if (rmv) {
        if (cmv) s = fmaf(w00, r0[cm], s);
        s = fmaf(w01, r0[col], s);
        if (cpv) s = fmaf(w02, r0[cp], s);
    }
    if (cmv) s = fmaf(w10, r1[cm], s);
    s = fmaf(w11, r1[col], s);
    if (cpv) s = fmaf(w12, r1[cp], s);
    if (rpv) {
        if (cmv) s = fmaf(w20, r2[cm], s);
        s = fmaf(w21, r2[col], s);
        if (cpv) s = fmaf(w22, r2[cp], s);
    }
    dst[((size_t)b * C_ + c) * HW_ + (size_t)row * W_ + col] = s;
}

// S-GEMM partials per (b,h,chunk of 256 px): S[48][48] + qss[48] + kss[48].
// Fixed-order deterministic reduction; LDS for partials reuses qs/ks.
__global__ __launch_bounds__(256, 4) void k3_qk(
    const float* __restrict__ qb, const float* __restrict__ kb,
    float* __restrict__ Sp) {
    __shared__ float qs[48 * 66];   // also red0 (needs 2304)
    __shared__ float ks[48 * 66];   // also red1
    __shared__ float sredN[4 * 96];
    int t = threadIdx.x;
    int chunk = blockIdx.x, h = blockIdx.y, b = blockIdx.z;
    int w = t >> 6, l = t & 63;
    int ci = (l & 7) * 6, di = (l >> 3) * 6;
    const float* qrow = qb + ((size_t)b * C_ + h * CH_) * HW_;
    const float* krow = kb + ((size_t)b * C_ + h * CH_) * HW_;
    float S[6][6];
#pragma unroll
    for (int uc = 0; uc < 6; ++uc)
#pragma unroll
        for (int ud = 0; ud < 6; ++ud) S[uc][ud] = 0.f;
    float qss[6] = {0, 0, 0, 0, 0, 0}, kss[6] = {0, 0, 0, 0, 0, 0};

    for (int s = 0; s < 4; ++s) {   // 4 stages x 64 px = 256 px
        __syncthreads();
        int base = chunk * 256 + s * 64;
        for (int idx = t; idx < 48 * 64; idx += 256) {
            int c = idx >> 6, j = idx & 63;
            qs[c * 66 + j] = qrow[(size_t)c * HW_ + base + j];
            ks[c * 66 + j] = krow[(size_t)c * HW_ + base + j];
        }
        __syncthreads();
        for (int jo = 0; jo < 16; ++jo) {
            int jj = w * 16 + jo;
            float rq[6], rk[6];
#pragma unroll
            for (int u = 0; u < 6; ++u) {
                rq[u] = qs[(ci + u) * 66 + jj];
                rk[u] = ks[(di + u) * 66 + jj];
            }
#pragma unroll
            for (int uc = 0; uc < 6; ++uc)
#pragma unroll
                for (int ud = 0; ud < 6; ++ud)
                    S[uc][ud] = fmaf(rq[uc], rk[ud], S[uc][ud]);
            if (l < 8) {
#pragma unroll
                for (int u = 0; u < 6; ++u) qss[u] = fmaf(rq[u], rq[u], qss[u]);
            }
            if ((l & 7) == 0) {
#pragma unroll
                for (int u = 0; u < 6; ++u) kss[u] = fmaf(rk[u], rk[u], kss[u]);
            }
        }
    }
    // deterministic reduce: red[w&1] gets (w) then (+w+2); final = red0+red1
    __syncthreads();
    float* red0 = qs;
    float* red1 = ks;
    if (w < 2) {
        float* r = (w == 0) ? red0 : red1;
#pragma unroll
        for (int uc = 0; uc < 6; ++uc)
#pragma unroll
            for (int ud = 0; ud < 6; ++ud)
                r[(ci + uc) * 48 + (di + ud)] = S[uc][ud];
    }
    if (l < 8) {
#pragma unroll
        for (int u = 0; u < 6; ++u) sredN[w * 96 + ci + u] = qss[u];
    }
    if ((l & 7) == 0) {
#pragma unroll
        for (int u = 0; u < 6; ++u) sredN[w * 96 + 48 + di + u] = kss[u];
    }
    __syncthreads();
    if (w >= 2) {
        float* r = (w == 2) ? red0 : red1;
#pragma unroll
        for (int uc = 0; uc < 6; ++uc)
#pragma unroll
            for (int ud = 0; ud < 6; ++ud)
                r[(ci + uc) * 48 + (di + ud)] += S[uc][ud];
    }
    __syncthreads();
    size_t ob = ((size_t)(b * HEADS_ + h) * CHUNKS_ + chunk) * 2400;
    for (int idx = t; idx < 2304; idx += 256)
        Sp[ob + idx] = red0[idx] + red1[idx];
    if (t < 96)
        Sp[ob + 2304 + t] = (sredN[t] + sredN[96 + t]) +
                            (sredN[192 + t] + sredN[288 + t]);
}

// reduce partials -> norms -> softmax -> MT[cg][o] = sum_c wp[o][h*48+c]*A[c][d]
__global__ __launch_bounds__(256, 2) void k4_softmax(
    const float* __restrict__ Sp, const float* __restrict__ wp,
    const float* __restrict__ temp, float* __restrict__ MT) {
    __shared__ float sS[2304];
    __shared__ float sN[96];
    int t = threadIdx.x;
    int bh = blockIdx.x;
    int b = bh >> 2, h = bh & 3;
    size_t base = (size_t)bh * CHUNKS_ * 2400;
    for (int idx = t; idx < 2400; idx += 256) {
        float v = 0.f;
        for (int ch = 0; ch < CHUNKS_; ++ch) v += Sp[base + (size_t)ch * 2400 + idx];
        if (idx < 2304) sS[idx] = v; else sN[idx - 2304] = v;
    }
    __syncthreads();
    if (t < 96) sN[t] = fmaxf(sqrtf(fmaxf(sN[t], 0.f)), 1e-12f);
    __syncthreads();
    if (t < 48) {
        float tv = temp[h];
        float qn = sN[t];
        float L[48];
        float m = -1e30f;
#pragma unroll
        for (int d = 0; d < 48; ++d) {
            float xv = sS[t * 48 + d] * tv / (qn * sN[48 + d]);
            L[d] = xv;
            m = fmaxf(m, xv);
        }
        float sum = 0.f;
#pragma unroll
        for (int d = 0; d < 48; ++d) {
            float e = expf(L[d] - m);
            L[d] = e;
            sum += e;
        }
        float inv = 1.f / sum;
#pragma unroll
        for (int d = 0; d < 48; ++d) sS[t * 48 + d] = L[d] * inv;
    }
    __syncthreads();
    for (int idx = t; idx < 48 * 192; idx += 256) {
        int d = idx / 192, o = idx % 192;
        const float* wpo = wp + (size_t)o * C_ + h * CH_;
        float sum = 0.f;
#pragma unroll
        for (int c = 0; c < 48; ++c) sum = fmaf(wpo[c], sS[c * 48 + d], sum);
        MT[(size_t)b * C_ * C_ + (size_t)(h * CH_ + d) * C_ + o] = sum;
    }
}

// out[b][oc0+o][p] = sum_c MT[b][c][oc0+o] * v[b][c][p]  (plain tiled GEMM)
__global__ __launch_bounds__(256, 4) void k5_out(
    const float* __restrict__ MT, const float* __restrict__ v,
    float* __restrict__ dout) {
    int t = threadIdx.x;
    int p = blockIdx.x * 256 + t;
    int oc0 = blockIdx.y * 64;
    int b = blockIdx.z;
    const float* vb = v + (size_t)b * C_ * HW_ + p;
    const float* MTb = MT + (size_t)b * C_ * C_;
    float acc[64];
#pragma unroll
    for (int o = 0; o < 64; ++o) acc[o] = 0.f;
    float vv = vb[0];
    for (int c = 0; c < C_; ++c) {
        float vn = (c + 1 < C_) ? vb[(size_t)(c + 1) * HW_] : 0.f;
        const float* mrow = MTb + c * C_ + oc0;  // uniform -> s_load
#pragma unroll
        for (int o = 0; o < 64; ++o) acc[o] = fmaf(vv, mrow[o], acc[o]);
        vv = vn;
    }
    float* db = dout + ((size_t)b * C_ + oc0) * HW_ + p;
#pragma unroll
    for (int o = 0; o < 64; ++o) db[(size_t)o * HW_] = acc[o];
}

extern "C" void kernel_launch(void* const* d_in, const int* in_sizes, int n_in,
                              void* d_out, int out_size, void* d_ws, size_t ws_size,
                              hipStream_t stream) {
    const float* x     = (const float*)d_in[0];
    const float* wqkv  = (const float*)d_in[1];
    const float* wdw   = (const float*)d_in[2];
    const float* wproj = (const float*)d_in[3];
    const float* temp  = (const float*)d_in[4];
    float* out = (float*)d_out;
    float* ws  = (float*)d_ws;

    float* wqT = ws + OFF_WQT;
    float* MT  = ws + OFF_MT;
    float* y1  = ws + OFF_Y1;
    float* Sp  = ws + OFF_Y1;   // aliases y1 (dead between k2(g=1) and k1(g=2))
    float* q   = ws + OFF_Q;
    float* k   = ws + OFF_K;
    float* v   = ws + OFF_Q;    // v reuses q slab after k3

    hipLaunchKernelGGL(k0_transpose, dim3(432), dim3(256), 0, stream, wqkv, wqT);
    // q then k
    hipLaunchKernelGGL(k1_conv1x1, dim3(64, 3, 4), dim3(256), 0, stream, x, wqT, y1, 0);
    hipLaunchKernelGGL(k2_dwconv, dim3(64, 192, 4), dim3(256), 0, stream, y1, wdw, q, 0);
    hipLaunchKernelGGL(k1_conv1x1, dim3(64, 3, 4), dim3(256), 0, stream, x, wqT, y1, 1);
    hipLaunchKernelGGL(k2_dwconv, dim3(64, 192, 4), dim3(256), 0, stream, y1, wdw, k, 1);
    // attention matrix -> MT
    hipLaunchKernelGGL(k3_qk, dim3(CHUNKS_, 4, 4), dim3(256), 0, stream, q, k, Sp);
    hipLaunchKernelGGL(k4_softmax, dim3(16), dim3(256), 0, stream, Sp, wproj, temp, MT);
    // v (into q slab), then output GEMM
    hipLaunchKernelGGL(k1_conv1x1, dim3(64, 3, 4), dim3(256), 0, stream, x, wqT, y1, 2);
    hipLaunchKernelGGL(k2_dwconv, dim3(64, 192, 4), dim3(256), 0, stream, y1, wdw, v, 2);
    hipLaunchKernelGGL(k5_out, dim3(64, 3, 4), dim3(256), 0, stream, MT, v, out);
}

// Round 3
// 452.392 us; speedup vs baseline: 2.2334x; 1.7426x over previous
//
#include <hip/hip_runtime.h>
#include <hip/hip_bf16.h>
#include <math.h>

// Restormer-style channel attention. Round 3: split-bf16 MFMA GEMMs.
// B=4, C=192, H=W=128, HEADS=4, ch=48, HW=16384.
//
// GEMMs (k1 conv1x1 x3, k5 proj@v) use mfma_f32_16x16x32_bf16 with
// 3-term hi/lo split: acc += xh*wh + xh*wl + xl*wh  (rel err ~1.6e-5).
// K-order invariance: A and B frags use the same (lane>>4,j)->k map, so any
// HW intra-K permutation cancels. C/D layout per guide (m89): col=lane&15,
// row=4*(lane>>4)+reg.
//
// ws (bytes): wqkvH 0..221184, wqkvL ..442368, MTh ..737280, MTl ..1032192,
// y1/Sp ..51363840, q/v ..101695488, k ..152027136  (= round-2's proven size)

#define B_ 4
#define C_ 192
#define H_ 128
#define W_ 128
#define HW_ 16384
#define HEADS_ 4
#define CH_ 48
#define CHUNKS_ 64

typedef __attribute__((ext_vector_type(8))) __bf16 bf16x8;
typedef __attribute__((ext_vector_type(8))) unsigned short u16x8;
typedef __attribute__((ext_vector_type(4))) float f32x4;

__device__ __forceinline__ unsigned short rne_bf16(float f) {
    unsigned int u = __float_as_uint(f);
    u += 0x7FFFu + ((u >> 16) & 1u);
    return (unsigned short)(u >> 16);
}
__device__ __forceinline__ float bf16_f32(unsigned short h) {
    return __uint_as_float(((unsigned int)h) << 16);
}

// split weights into bf16 hi/lo
__global__ void k0_split(const float* __restrict__ wq,
                         unsigned short* __restrict__ wH,
                         unsigned short* __restrict__ wL, int n) {
    int idx = blockIdx.x * 256 + threadIdx.x;
    if (idx < n) {
        float f = wq[idx];
        unsigned short h = rne_bf16(f);
        wH[idx] = h;
        wL[idx] = rne_bf16(f - bf16_f32(h));
    }
}

// Y[b][m0+..][p] = sum_k A[m][k] * X[b][k][p], M=192, K=192, split-bf16 MFMA.
// Block: 64 m x 256 px, 4 waves (each 64m x 64px). aStrideB: A per-batch stride.
__global__ __launch_bounds__(256, 2) void kg_mfma(
    const unsigned short* __restrict__ Ah, const unsigned short* __restrict__ Al,
    int aStrideB, const float* __restrict__ X, float* __restrict__ Y) {
    __shared__ unsigned short AhL[64 * 40];
    __shared__ unsigned short AlL[64 * 40];
    __shared__ unsigned short BhL[256 * 40];
    __shared__ unsigned short BlL[256 * 40];
    int t = threadIdx.x;
    int wave = t >> 6, lane = t & 63;
    int lm = lane & 15, kg = lane >> 4;
    int p0 = blockIdx.x * 256;
    int m0 = blockIdx.y * 64;
    int b = blockIdx.z;
    const unsigned short* Abh = Ah + (size_t)b * aStrideB;
    const unsigned short* Abl = Al + (size_t)b * aStrideB;
    const float* Xb = X + (size_t)b * C_ * HW_ + p0 + t;

    f32x4 acc[4][4];
#pragma unroll
    for (int mi = 0; mi < 4; ++mi)
#pragma unroll
        for (int ni = 0; ni < 4; ++ni) acc[mi][ni] = (f32x4)(0.f);

    int ar = t >> 2, ac = (t & 3) * 8;  // A-stage: row 0..63, 8-col chunk

    for (int s = 0; s < 6; ++s) {
        int k0 = s * 32;
        __syncthreads();
        // stage A tile [64][32] hi/lo
        *(u16x8*)&AhL[ar * 40 + ac] =
            *(const u16x8*)&Abh[(size_t)(m0 + ar) * C_ + k0 + ac];
        *(u16x8*)&AlL[ar * 40 + ac] =
            *(const u16x8*)&Abl[(size_t)(m0 + ar) * C_ + k0 + ac];
        // stage B tile [256 px][32 k]: thread owns px=t, loads 32 strided dwords
        const float* xp = Xb + (size_t)k0 * HW_;
        float xv[32];
#pragma unroll
        for (int i = 0; i < 32; ++i) xv[i] = xp[(size_t)i * HW_];
#pragma unroll
        for (int c8 = 0; c8 < 4; ++c8) {
            u16x8 hh, ll;
#pragma unroll
            for (int j = 0; j < 8; ++j) {
                float f = xv[c8 * 8 + j];
                unsigned short h = rne_bf16(f);
                hh[j] = h;
                ll[j] = rne_bf16(f - bf16_f32(h));
            }
            *(u16x8*)&BhL[t * 40 + c8 * 8] = hh;
            *(u16x8*)&BlL[t * 40 + c8 * 8] = ll;
        }
        __syncthreads();
        // fragments: A row = lm+16*mi, k = 8*kg+j; B col-row = wave*64+16*ni+lm
        bf16x8 fah[4], fal[4], fbh[4], fbl[4];
#pragma unroll
        for (int mi = 0; mi < 4; ++mi) {
            int ro = (lm + mi * 16) * 40 + kg * 8;
            fah[mi] = __builtin_bit_cast(bf16x8, *(const u16x8*)&AhL[ro]);
            fal[mi] = __builtin_bit_cast(bf16x8, *(const u16x8*)&AlL[ro]);
        }
#pragma unroll
        for (int ni = 0; ni < 4; ++ni) {
            int ro = (wave * 64 + ni * 16 + lm) * 40 + kg * 8;
            fbh[ni] = __builtin_bit_cast(bf16x8, *(const u16x8*)&BhL[ro]);
            fbl[ni] = __builtin_bit_cast(bf16x8, *(const u16x8*)&BlL[ro]);
        }
#pragma unroll
        for (int mi = 0; mi < 4; ++mi)
#pragma unroll
            for (int ni = 0; ni < 4; ++ni) {
                acc[mi][ni] = __builtin_amdgcn_mfma_f32_16x16x32_bf16(
                    fah[mi], fbh[ni], acc[mi][ni], 0, 0, 0);
                acc[mi][ni] = __builtin_amdgcn_mfma_f32_16x16x32_bf16(
                    fah[mi], fbl[ni], acc[mi][ni], 0, 0, 0);
                acc[mi][ni] = __builtin_amdgcn_mfma_f32_16x16x32_bf16(
                    fal[mi], fbh[ni], acc[mi][ni], 0, 0, 0);
            }
    }
    // epilogue: D col = lane&15 (px), row = 4*kg + r (m)
#pragma unroll
    for (int mi = 0; mi < 4; ++mi)
#pragma unroll
        for (int ni = 0; ni < 4; ++ni) {
            int oc = m0 + mi * 16 + kg * 4;
            int px = p0 + wave * 64 + ni * 16 + lm;
            float* yp = Y + ((size_t)b * C_ + oc) * HW_ + px;
#pragma unroll
            for (int r = 0; r < 4; ++r) yp[(size_t)r * HW_] = acc[mi][ni][r];
        }
}

// depthwise 3x3, zero pad
__global__ __launch_bounds__(256, 8) void k2_dwconv(
    const float* __restrict__ y1, const float* __restrict__ wdw,
    float* __restrict__ dst, int g) {
    int t = threadIdx.x;
    int c = blockIdx.y, b = blockIdx.z;
    int row = blockIdx.x * 2 + (t >> 7);
    int col = t & 127;
    const float* yp = y1 + ((size_t)b * C_ + c) * HW_;
    const float* wd = wdw + (size_t)(g * C_ + c) * 9;
    float w00 = wd[0], w01 = wd[1], w02 = wd[2];
    float w10 = wd[3], w11 = wd[4], w12 = wd[5];
    float w20 = wd[6], w21 = wd[7], w22 = wd[8];
    int rm = row - 1, rp = row + 1, cm = col - 1, cp = col + 1;
    bool rmv = rm >= 0, rpv = rp < H_, cmv = cm >= 0, cpv = cp < W_;
    const float* r0 = yp + (size_t)rm * W_;
    const float* r1 = yp + (size_t)row * W_;
    const float* r2 = yp + (size_t)rp * W_;
    float s = 0.f;
    if (rmv) {
        if (cmv) s = fmaf(w00, r0[cm], s);
        s = fmaf(w01, r0[col], s);
        if (cpv) s = fmaf(w02, r0[cp], s);
    }
    if (cmv) s = fmaf(w10, r1[cm], s);
    s = fmaf(w11, r1[col], s);
    if (cpv) s = fmaf(w12, r1[cp], s);
    if (rpv) {
        if (cmv) s = fmaf(w20, r2[cm], s);
        s = fmaf(w21, r2[col], s);
        if (cpv) s = fmaf(w22, r2[cp], s);
    }
    dst[((size_t)b * C_ + c) * HW_ + (size_t)row * W_ + col] = s;
}

// S-GEMM partials per (b,h,chunk of 256 px): S[48][48] + qss[48] + kss[48]
__global__ __launch_bounds__(256, 4) void k3_qk(
    const float* __restrict__ qb, const float* __restrict__ kb,
    float* __restrict__ Sp) {
    __shared__ float qs[48 * 66];
    __shared__ float ks[48 * 66];
    __shared__ float sredN[4 * 96];
    int t = threadIdx.x;
    int chunk = blockIdx.x, h = blockIdx.y, b = blockIdx.z;
    int w = t >> 6, l = t & 63;
    int ci = (l & 7) * 6, di = (l >> 3) * 6;
    const float* qrow = qb + ((size_t)b * C_ + h * CH_) * HW_;
    const float* krow = kb + ((size_t)b * C_ + h * CH_) * HW_;
    float S[6][6];
#pragma unroll
    for (int uc = 0; uc < 6; ++uc)
#pragma unroll
        for (int ud = 0; ud < 6; ++ud) S[uc][ud] = 0.f;
    float qss[6] = {0, 0, 0, 0, 0, 0}, kss[6] = {0, 0, 0, 0, 0, 0};

    for (int s = 0; s < 4; ++s) {
        __syncthreads();
        int base = chunk * 256 + s * 64;
        for (int idx = t; idx < 48 * 64; idx += 256) {
            int c = idx >> 6, j = idx & 63;
            qs[c * 66 + j] = qrow[(size_t)c * HW_ + base + j];
            ks[c * 66 + j] = krow[(size_t)c * HW_ + base + j];
        }
        __syncthreads();
        for (int jo = 0; jo < 16; ++jo) {
            int jj = w * 16 + jo;
            float rq[6], rk[6];
#pragma unroll
            for (int u = 0; u < 6; ++u) {
                rq[u] = qs[(ci + u) * 66 + jj];
                rk[u] = ks[(di + u) * 66 + jj];
            }
#pragma unroll
            for (int uc = 0; uc < 6; ++uc)
#pragma unroll
                for (int ud = 0; ud < 6; ++ud)
                    S[uc][ud] = fmaf(rq[uc], rk[ud], S[uc][ud]);
            if (l < 8) {
#pragma unroll
                for (int u = 0; u < 6; ++u) qss[u] = fmaf(rq[u], rq[u], qss[u]);
            }
            if ((l & 7) == 0) {
#pragma unroll
                for (int u = 0; u < 6; ++u) kss[u] = fmaf(rk[u], rk[u], kss[u]);
            }
        }
    }
    __syncthreads();
    float* red0 = qs;
    float* red1 = ks;
    if (w < 2) {
        float* r = (w == 0) ? red0 : red1;
#pragma unroll
        for (int uc = 0; uc < 6; ++uc)
#pragma unroll
            for (int ud = 0; ud < 6; ++ud)
                r[(ci + uc) * 48 + (di + ud)] = S[uc][ud];
    }
    if (l < 8) {
#pragma unroll
        for (int u = 0; u < 6; ++u) sredN[w * 96 + ci + u] = qss[u];
    }
    if ((l & 7) == 0) {
#pragma unroll
        for (int u = 0; u < 6; ++u) sredN[w * 96 + 48 + di + u] = kss[u];
    }
    __syncthreads();
    if (w >= 2) {
        float* r = (w == 2) ? red0 : red1;
#pragma unroll
        for (int uc = 0; uc < 6; ++uc)
#pragma unroll
            for (int ud = 0; ud < 6; ++ud)
                r[(ci + uc) * 48 + (di + ud)] += S[uc][ud];
    }
    __syncthreads();
    size_t ob = ((size_t)(b * HEADS_ + h) * CHUNKS_ + chunk) * 2400;
    for (int idx = t; idx < 2304; idx += 256)
        Sp[ob + idx] = red0[idx] + red1[idx];
    if (t < 96)
        Sp[ob + 2304 + t] = (sredN[t] + sredN[96 + t]) +
                            (sredN[192 + t] + sredN[288 + t]);
}

// reduce partials -> norms -> softmax -> M = wproj . blockdiag(attn),
// emitted as split-bf16 MTh/MTl in [b][o][cg] layout (A-operand of k5).
__global__ __launch_bounds__(256, 2) void k4_softmax(
    const float* __restrict__ Sp, const float* __restrict__ wp,
    const float* __restrict__ temp,
    unsigned short* __restrict__ MTh, unsigned short* __restrict__ MTl) {
    __shared__ float sS[2304];
    __shared__ float sN[96];
    int t = threadIdx.x;
    int bh = blockIdx.x;
    int b = bh >> 2, h = bh & 3;
    size_t base = (size_t)bh * CHUNKS_ * 2400;
    for (int idx = t; idx < 2400; idx += 256) {
        float v = 0.f;
        for (int ch = 0; ch < CHUNKS_; ++ch) v += Sp[base + (size_t)ch * 2400 + idx];
        if (idx < 2304) sS[idx] = v; else sN[idx - 2304] = v;
    }
    __syncthreads();
    if (t < 96) sN[t] = fmaxf(sqrtf(fmaxf(sN[t], 0.f)), 1e-12f);
    __syncthreads();
    if (t < 48) {
        float tv = temp[h];
        float qn = sN[t];
        float L[48];
        float m = -1e30f;
#pragma unroll
        for (int d = 0; d < 48; ++d) {
            float xv = sS[t * 48 + d] * tv / (qn * sN[48 + d]);
            L[d] = xv;
            m = fmaxf(m, xv);
        }
        float sum = 0.f;
#pragma unroll
        for (int d = 0; d < 48; ++d) {
            float e = expf(L[d] - m);
            L[d] = e;
            sum += e;
        }
        float inv = 1.f / sum;
#pragma unroll
        for (int d = 0; d < 48; ++d) sS[t * 48 + d] = L[d] * inv;
    }
    __syncthreads();
    for (int idx = t; idx < 48 * 192; idx += 256) {
        int d = idx / 192, o = idx % 192;
        const float* wpo = wp + (size_t)o * C_ + h * CH_;
        float sum = 0.f;
#pragma unroll
        for (int c = 0; c < 48; ++c) sum = fmaf(wpo[c], sS[c * 48 + d], sum);
        size_t oi = ((size_t)b * C_ + o) * C_ + h * CH_ + d;
        unsigned short hh = rne_bf16(sum);
        MTh[oi] = hh;
        MTl[oi] = rne_bf16(sum - bf16_f32(hh));
    }
}

extern "C" void kernel_launch(void* const* d_in, const int* in_sizes, int n_in,
                              void* d_out, int out_size, void* d_ws, size_t ws_size,
                              hipStream_t stream) {
    const float* x     = (const float*)d_in[0];
    const float* wqkv  = (const float*)d_in[1];
    const float* wdw   = (const float*)d_in[2];
    const float* wproj = (const float*)d_in[3];
    const float* temp  = (const float*)d_in[4];
    float* out = (float*)d_out;
    char* ws = (char*)d_ws;

    unsigned short* wqkvH = (unsigned short*)(ws + 0);          // 221184 B
    unsigned short* wqkvL = (unsigned short*)(ws + 221184);     // 221184 B
    unsigned short* MTh   = (unsigned short*)(ws + 442368);     // 294912 B
    unsigned short* MTl   = (unsigned short*)(ws + 737280);     // 294912 B
    float* y1 = (float*)(ws + 1032192);                         // 50331648 B
    float* Sp = y1;                                             // aliases y1
    float* q  = (float*)(ws + 51363840);                        // 50331648 B
    float* k  = (float*)(ws + 101695488);                       // 50331648 B
    float* v  = q;                                              // reuses q slab

    hipLaunchKernelGGL(k0_split, dim3(432), dim3(256), 0, stream,
                       wqkv, wqkvH, wqkvL, 576 * 192);
    // q
    hipLaunchKernelGGL(kg_mfma, dim3(64, 3, 4), dim3(256), 0, stream,
                       wqkvH, wqkvL, 0, x, y1);
    hipLaunchKernelGGL(k2_dwconv, dim3(64, 192, 4), dim3(256), 0, stream, y1, wdw, q, 0);
    // k
    hipLaunchKernelGGL(kg_mfma, dim3(64, 3, 4), dim3(256), 0, stream,
                       wqkvH + 192 * 192, wqkvL + 192 * 192, 0, x, y1);
    hipLaunchKernelGGL(k2_dwconv, dim3(64, 192, 4), dim3(256), 0, stream, y1, wdw, k, 1);
    // attention -> MT (split)
    hipLaunchKernelGGL(k3_qk, dim3(CHUNKS_, 4, 4), dim3(256), 0, stream, q, k, Sp);
    hipLaunchKernelGGL(k4_softmax, dim3(16), dim3(256), 0, stream, Sp, wproj, temp, MTh, MTl);
    // v (into q slab)
    hipLaunchKernelGGL(kg_mfma, dim3(64, 3, 4), dim3(256), 0, stream,
                       wqkvH + 2 * 192 * 192, wqkvL + 2 * 192 * 192, 0, x, y1);
    hipLaunchKernelGGL(k2_dwconv, dim3(64, 192, 4), dim3(256), 0, stream, y1, wdw, v, 2);
    // out = M @ v
    hipLaunchKernelGGL(kg_mfma, dim3(64, 3, 4), dim3(256), 0, stream,
                       MTh, MTl, C_ * C_, v, out);
}

// Round 4
// 367.023 us; speedup vs baseline: 2.7528x; 1.2326x over previous
//
#include <hip/hip_runtime.h>
#include <hip/hip_bf16.h>
#include <math.h>

// Restormer-style channel attention. Round 4: k4 split (occupancy+spill fix),
// packed-split v for k5, cheaper trunc-hi split, kg occupancy 3 blocks/CU.
// B=4, C=192, H=W=128, HEADS=4, ch=48, HW=16384.

#define B_ 4
#define C_ 192
#define H_ 128
#define W_ 128
#define HW_ 16384
#define HEADS_ 4
#define CH_ 48
#define CHUNKS_ 64

typedef __attribute__((ext_vector_type(8))) __bf16 bf16x8;
typedef __attribute__((ext_vector_type(8))) unsigned short u16x8;
typedef __attribute__((ext_vector_type(4))) float f32x4;

__device__ __forceinline__ unsigned short rne_bf16(float f) {
    unsigned int u = __float_as_uint(f);
    u += 0x7FFFu + ((u >> 16) & 1u);
    return (unsigned short)(u >> 16);
}
__device__ __forceinline__ float bf16_f32(unsigned short h) {
    return __uint_as_float(((unsigned int)h) << 16);
}

// split weights into bf16 hi/lo (RNE both)
__global__ void k0_split(const float* __restrict__ wq,
                         unsigned short* __restrict__ wH,
                         unsigned short* __restrict__ wL, int n) {
    int idx = blockIdx.x * 256 + threadIdx.x;
    if (idx < n) {
        float f = wq[idx];
        unsigned short h = rne_bf16(f);
        wH[idx] = h;
        wL[idx] = rne_bf16(f - bf16_f32(h));
    }
}

// ---------------- GEMM: Y[b][m][p] = sum_k A[m][k] * X[b][k][p] -------------
// f32-input variant (in-kernel trunc-hi/rne-lo split of X).
__global__ __launch_bounds__(256, 3) void kg_mfma(
    const unsigned short* __restrict__ Ah, const unsigned short* __restrict__ Al,
    int aStrideB, const float* __restrict__ X, float* __restrict__ Y) {
    __shared__ unsigned short AhL[64 * 40];
    __shared__ unsigned short AlL[64 * 40];
    __shared__ unsigned short BhL[256 * 40];
    __shared__ unsigned short BlL[256 * 40];
    int t = threadIdx.x;
    int wave = t >> 6, lane = t & 63;
    int lm = lane & 15, kg = lane >> 4;
    int p0 = blockIdx.x * 256;
    int m0 = blockIdx.y * 64;
    int b = blockIdx.z;
    const unsigned short* Abh = Ah + (size_t)b * aStrideB;
    const unsigned short* Abl = Al + (size_t)b * aStrideB;
    const float* Xb = X + (size_t)b * C_ * HW_ + p0 + t;

    f32x4 acc[4][4];
#pragma unroll
    for (int mi = 0; mi < 4; ++mi)
#pragma unroll
        for (int ni = 0; ni < 4; ++ni) acc[mi][ni] = (f32x4)(0.f);

    int ar = t >> 2, ac = (t & 3) * 8;

    for (int s = 0; s < 6; ++s) {
        int k0 = s * 32;
        __syncthreads();
        *(u16x8*)&AhL[ar * 40 + ac] =
            *(const u16x8*)&Abh[(size_t)(m0 + ar) * C_ + k0 + ac];
        *(u16x8*)&AlL[ar * 40 + ac] =
            *(const u16x8*)&Abl[(size_t)(m0 + ar) * C_ + k0 + ac];
#pragma unroll
        for (int half = 0; half < 2; ++half) {
            const float* xp = Xb + (size_t)(k0 + half * 16) * HW_;
            float xv[16];
#pragma unroll
            for (int i = 0; i < 16; ++i) xv[i] = xp[(size_t)i * HW_];
#pragma unroll
            for (int c8 = 0; c8 < 2; ++c8) {
                u16x8 hh, ll;
#pragma unroll
                for (int j = 0; j < 8; ++j) {
                    float f = xv[c8 * 8 + j];
                    unsigned int u = __float_as_uint(f);
                    hh[j] = (unsigned short)(u >> 16);  // trunc hi
                    float r = f - __uint_as_float(u & 0xFFFF0000u);
                    ll[j] = rne_bf16(r);
                }
                *(u16x8*)&BhL[t * 40 + half * 16 + c8 * 8] = hh;
                *(u16x8*)&BlL[t * 40 + half * 16 + c8 * 8] = ll;
            }
        }
        __syncthreads();
        bf16x8 fah[4], fal[4], fbh[4], fbl[4];
#pragma unroll
        for (int mi = 0; mi < 4; ++mi) {
            int ro = (lm + mi * 16) * 40 + kg * 8;
            fah[mi] = __builtin_bit_cast(bf16x8, *(const u16x8*)&AhL[ro]);
            fal[mi] = __builtin_bit_cast(bf16x8, *(const u16x8*)&AlL[ro]);
        }
#pragma unroll
        for (int ni = 0; ni < 4; ++ni) {
            int ro = (wave * 64 + ni * 16 + lm) * 40 + kg * 8;
            fbh[ni] = __builtin_bit_cast(bf16x8, *(const u16x8*)&BhL[ro]);
            fbl[ni] = __builtin_bit_cast(bf16x8, *(const u16x8*)&BlL[ro]);
        }
#pragma unroll
        for (int mi = 0; mi < 4; ++mi)
#pragma unroll
            for (int ni = 0; ni < 4; ++ni) {
                acc[mi][ni] = __builtin_amdgcn_mfma_f32_16x16x32_bf16(
                    fah[mi], fbh[ni], acc[mi][ni], 0, 0, 0);
                acc[mi][ni] = __builtin_amdgcn_mfma_f32_16x16x32_bf16(
                    fah[mi], fbl[ni], acc[mi][ni], 0, 0, 0);
                acc[mi][ni] = __builtin_amdgcn_mfma_f32_16x16x32_bf16(
                    fal[mi], fbh[ni], acc[mi][ni], 0, 0, 0);
            }
    }
#pragma unroll
    for (int mi = 0; mi < 4; ++mi)
#pragma unroll
        for (int ni = 0; ni < 4; ++ni) {
            int oc = m0 + mi * 16 + kg * 4;
            int px = p0 + wave * 64 + ni * 16 + lm;
            float* yp = Y + ((size_t)b * C_ + oc) * HW_ + px;
#pragma unroll
            for (int r = 0; r < 4; ++r) yp[(size_t)r * HW_] = acc[mi][ni][r];
        }
}

// packed-split-input variant (X = u32: lo16=hi-bf16, hi16=lo-bf16)
__global__ __launch_bounds__(256, 3) void kg_mfma_p(
    const unsigned short* __restrict__ Ah, const unsigned short* __restrict__ Al,
    int aStrideB, const unsigned int* __restrict__ X, float* __restrict__ Y) {
    __shared__ unsigned short AhL[64 * 40];
    __shared__ unsigned short AlL[64 * 40];
    __shared__ unsigned short BhL[256 * 40];
    __shared__ unsigned short BlL[256 * 40];
    int t = threadIdx.x;
    int wave = t >> 6, lane = t & 63;
    int lm = lane & 15, kg = lane >> 4;
    int p0 = blockIdx.x * 256;
    int m0 = blockIdx.y * 64;
    int b = blockIdx.z;
    const unsigned short* Abh = Ah + (size_t)b * aStrideB;
    const unsigned short* Abl = Al + (size_t)b * aStrideB;
    const unsigned int* Xb = X + (size_t)b * C_ * HW_ + p0 + t;

    f32x4 acc[4][4];
#pragma unroll
    for (int mi = 0; mi < 4; ++mi)
#pragma unroll
        for (int ni = 0; ni < 4; ++ni) acc[mi][ni] = (f32x4)(0.f);

    int ar = t >> 2, ac = (t & 3) * 8;

    for (int s = 0; s < 6; ++s) {
        int k0 = s * 32;
        __syncthreads();
        *(u16x8*)&AhL[ar * 40 + ac] =
            *(const u16x8*)&Abh[(size_t)(m0 + ar) * C_ + k0 + ac];
        *(u16x8*)&AlL[ar * 40 + ac] =
            *(const u16x8*)&Abl[(size_t)(m0 + ar) * C_ + k0 + ac];
#pragma unroll
        for (int half = 0; half < 2; ++half) {
            const unsigned int* xp = Xb + (size_t)(k0 + half * 16) * HW_;
            unsigned int xv[16];
#pragma unroll
            for (int i = 0; i < 16; ++i) xv[i] = xp[(size_t)i * HW_];
#pragma unroll
            for (int c8 = 0; c8 < 2; ++c8) {
                u16x8 hh, ll;
#pragma unroll
                for (int j = 0; j < 8; ++j) {
                    unsigned int u = xv[c8 * 8 + j];
                    hh[j] = (unsigned short)(u & 0xFFFFu);
                    ll[j] = (unsigned short)(u >> 16);
                }
                *(u16x8*)&BhL[t * 40 + half * 16 + c8 * 8] = hh;
                *(u16x8*)&BlL[t * 40 + half * 16 + c8 * 8] = ll;
            }
        }
        __syncthreads();
        bf16x8 fah[4], fal[4], fbh[4], fbl[4];
#pragma unroll
        for (int mi = 0; mi < 4; ++mi) {
            int ro = (lm + mi * 16) * 40 + kg * 8;
            fah[mi] = __builtin_bit_cast(bf16x8, *(const u16x8*)&AhL[ro]);
            fal[mi] = __builtin_bit_cast(bf16x8, *(const u16x8*)&AlL[ro]);
        }
#pragma unroll
        for (int ni = 0; ni < 4; ++ni) {
            int ro = (wave * 64 + ni * 16 + lm) * 40 + kg * 8;
            fbh[ni] = __builtin_bit_cast(bf16x8, *(const u16x8*)&BhL[ro]);
            fbl[ni] = __builtin_bit_cast(bf16x8, *(const u16x8*)&BlL[ro]);
        }
#pragma unroll
        for (int mi = 0; mi < 4; ++mi)
#pragma unroll
            for (int ni = 0; ni < 4; ++ni) {
                acc[mi][ni] = __builtin_amdgcn_mfma_f32_16x16x32_bf16(
                    fah[mi], fbh[ni], acc[mi][ni], 0, 0, 0);
                acc[mi][ni] = __builtin_amdgcn_mfma_f32_16x16x32_bf16(
                    fah[mi], fbl[ni], acc[mi][ni], 0, 0, 0);
                acc[mi][ni] = __builtin_amdgcn_mfma_f32_16x16x32_bf16(
                    fal[mi], fbh[ni], acc[mi][ni], 0, 0, 0);
            }
    }
#pragma unroll
    for (int mi = 0; mi < 4; ++mi)
#pragma unroll
        for (int ni = 0; ni < 4; ++ni) {
            int oc = m0 + mi * 16 + kg * 4;
            int px = p0 + wave * 64 + ni * 16 + lm;
            float* yp = Y + ((size_t)b * C_ + oc) * HW_ + px;
#pragma unroll
            for (int r = 0; r < 4; ++r) yp[(size_t)r * HW_] = acc[mi][ni][r];
        }
}

// depthwise 3x3, zero pad; pack=1 -> emit packed split-bf16 (u32)
__global__ __launch_bounds__(256, 8) void k2_dwconv(
    const float* __restrict__ y1, const float* __restrict__ wdw,
    float* __restrict__ dstF, unsigned int* __restrict__ dstP, int g, int pack) {
    int t = threadIdx.x;
    int c = blockIdx.y, b = blockIdx.z;
    int row = blockIdx.x * 2 + (t >> 7);
    int col = t & 127;
    const float* yp = y1 + ((size_t)b * C_ + c) * HW_;
    const float* wd = wdw + (size_t)(g * C_ + c) * 9;
    float w00 = wd[0], w01 = wd[1], w02 = wd[2];
    float w10 = wd[3], w11 = wd[4], w12 = wd[5];
    float w20 = wd[6], w21 = wd[7], w22 = wd[8];
    int rm = row - 1, rp = row + 1, cm = col - 1, cp = col + 1;
    bool rmv = rm >= 0, rpv = rp < H_, cmv = cm >= 0, cpv = cp < W_;
    const float* r0 = yp + (size_t)rm * W_;
    const float* r1 = yp + (size_t)row * W_;
    const float* r2 = yp + (size_t)rp * W_;
    float s = 0.f;
    if (rmv) {
        if (cmv) s = fmaf(w00, r0[cm], s);
        s = fmaf(w01, r0[col], s);
        if (cpv) s = fmaf(w02, r0[cp], s);
    }
    if (cmv) s = fmaf(w10, r1[cm], s);
    s = fmaf(w11, r1[col], s);
    if (cpv) s = fmaf(w12, r1[cp], s);
    if (rpv) {
        if (cmv) s = fmaf(w20, r2[cm], s);
        s = fmaf(w21, r2[col], s);
        if (cpv) s = fmaf(w22, r2[cp], s);
    }
    size_t oi = ((size_t)b * C_ + c) * HW_ + (size_t)row * W_ + col;
    if (pack) {
        unsigned int u = __float_as_uint(s);
        unsigned short h = (unsigned short)(u >> 16);  // trunc hi
        float r = s - __uint_as_float(u & 0xFFFF0000u);
        unsigned short l = rne_bf16(r);
        dstP[oi] = (unsigned int)h | ((unsigned int)l << 16);
    } else {
        dstF[oi] = s;
    }
}

// S-GEMM partials per (b,h,chunk of 256 px): S[48][48] + qss[48] + kss[48]
__global__ __launch_bounds__(256, 4) void k3_qk(
    const float* __restrict__ qb, const float* __restrict__ kb,
    float* __restrict__ Sp) {
    __shared__ float qs[48 * 66];
    __shared__ float ks[48 * 66];
    __shared__ float sredN[4 * 96];
    int t = threadIdx.x;
    int chunk = blockIdx.x, h = blockIdx.y, b = blockIdx.z;
    int w = t >> 6, l = t & 63;
    int ci = (l & 7) * 6, di = (l >> 3) * 6;
    const float* qrow = qb + ((size_t)b * C_ + h * CH_) * HW_;
    const float* krow = kb + ((size_t)b * C_ + h * CH_) * HW_;
    float S[6][6];
#pragma unroll
    for (int uc = 0; uc < 6; ++uc)
#pragma unroll
        for (int ud = 0; ud < 6; ++ud) S[uc][ud] = 0.f;
    float qss[6] = {0, 0, 0, 0, 0, 0}, kss[6] = {0, 0, 0, 0, 0, 0};

    for (int s = 0; s < 4; ++s) {
        __syncthreads();
        int base = chunk * 256 + s * 64;
        for (int idx = t; idx < 48 * 64; idx += 256) {
            int c = idx >> 6, j = idx & 63;
            qs[c * 66 + j] = qrow[(size_t)c * HW_ + base + j];
            ks[c * 66 + j] = krow[(size_t)c * HW_ + base + j];
        }
        __syncthreads();
        for (int jo = 0; jo < 16; ++jo) {
            int jj = w * 16 + jo;
            float rq[6], rk[6];
#pragma unroll
            for (int u = 0; u < 6; ++u) {
                rq[u] = qs[(ci + u) * 66 + jj];
                rk[u] = ks[(di + u) * 66 + jj];
            }
#pragma unroll
            for (int uc = 0; uc < 6; ++uc)
#pragma unroll
                for (int ud = 0; ud < 6; ++ud)
                    S[uc][ud] = fmaf(rq[uc], rk[ud], S[uc][ud]);
            if (l < 8) {
#pragma unroll
                for (int u = 0; u < 6; ++u) qss[u] = fmaf(rq[u], rq[u], qss[u]);
            }
            if ((l & 7) == 0) {
#pragma unroll
                for (int u = 0; u < 6; ++u) kss[u] = fmaf(rk[u], rk[u], kss[u]);
            }
        }
    }
    __syncthreads();
    float* red0 = qs;
    float* red1 = ks;
    if (w < 2) {
        float* r = (w == 0) ? red0 : red1;
#pragma unroll
        for (int uc = 0; uc < 6; ++uc)
#pragma unroll
            for (int ud = 0; ud < 6; ++ud)
                r[(ci + uc) * 48 + (di + ud)] = S[uc][ud];
    }
    if (l < 8) {
#pragma unroll
        for (int u = 0; u < 6; ++u) sredN[w * 96 + ci + u] = qss[u];
    }
    if ((l & 7) == 0) {
#pragma unroll
        for (int u = 0; u < 6; ++u) sredN[w * 96 + 48 + di + u] = kss[u];
    }
    __syncthreads();
    if (w >= 2) {
        float* r = (w == 2) ? red0 : red1;
#pragma unroll
        for (int uc = 0; uc < 6; ++uc)
#pragma unroll
            for (int ud = 0; ud < 6; ++ud)
                r[(ci + uc) * 48 + (di + ud)] += S[uc][ud];
    }
    __syncthreads();
    size_t ob = ((size_t)(b * HEADS_ + h) * CHUNKS_ + chunk) * 2400;
    for (int idx = t; idx < 2304; idx += 256)
        Sp[ob + idx] = red0[idx] + red1[idx];
    if (t < 96)
        Sp[ob + 2304 + t] = (sredN[t] + sredN[96 + t]) +
                            (sredN[192 + t] + sredN[288 + t]);
}

// parallel chunk-reduce: Sred[bh][0..2400) = sum over 64 chunk partials
__global__ __launch_bounds__(256, 8) void k4a_reduce(
    const float* __restrict__ Sp, float* __restrict__ Sred) {
    int idx = blockIdx.x * 256 + threadIdx.x;  // 38400 total
    if (idx >= 16 * 2400) return;
    int bh = idx / 2400, e = idx - bh * 2400;
    const float* p = Sp + (size_t)bh * CHUNKS_ * 2400 + e;
    float s = 0.f;
#pragma unroll 8
    for (int c = 0; c < CHUNKS_; ++c) s += p[(size_t)c * 2400];
    Sred[idx] = s;
}

// norms -> softmax (in-LDS) -> MT = wproj . blockdiag(attn), split-bf16 out
__global__ __launch_bounds__(256, 2) void k4b_softmax(
    const float* __restrict__ Sred, const float* __restrict__ wp,
    const float* __restrict__ temp,
    unsigned short* __restrict__ MTh, unsigned short* __restrict__ MTl) {
    __shared__ float sS[2304];       // scaled logits
    __shared__ float sT[2304];       // attn transposed [d][c]
    __shared__ float wpL[192 * 48];  // wproj head block [o][c]
    __shared__ float sNi[96];
    int t = threadIdx.x;
    int bh = blockIdx.x;
    int b = bh >> 2, h = bh & 3;
    const float* Sr = Sred + (size_t)bh * 2400;
    for (int idx = t; idx < 2304; idx += 256) sS[idx] = Sr[idx];
    if (t < 96) sNi[t] = 1.f / fmaxf(sqrtf(fmaxf(Sr[2304 + t], 0.f)), 1e-12f);
    for (int i = t; i < 192 * 48; i += 256) {
        int o = i / 48, c = i - o * 48;
        wpL[i] = wp[(size_t)o * C_ + h * CH_ + c];
    }
    __syncthreads();
    if (t < 48) {
        float rq = sNi[t] * temp[h];
        float m = -1e30f;
#pragma unroll
        for (int d = 0; d < 48; ++d) {
            float v = sS[t * 48 + d] * rq * sNi[48 + d];
            sS[t * 48 + d] = v;
            m = fmaxf(m, v);
        }
        float sum = 0.f;
#pragma unroll
        for (int d = 0; d < 48; ++d) {
            float e = expf(sS[t * 48 + d] - m);
            sT[d * 48 + t] = e;
            sum += e;
        }
        float inv = 1.f / sum;
#pragma unroll
        for (int d = 0; d < 48; ++d) sT[d * 48 + t] *= inv;
    }
    __syncthreads();
    for (int i = t; i < 48 * 192; i += 256) {
        int d = i / 192, o = i - d * 192;
        const float4* wv = (const float4*)&wpL[o * 48];
        const float4* pv = (const float4*)&sT[d * 48];
        float sum = 0.f;
#pragma unroll
        for (int c4 = 0; c4 < 12; ++c4) {
            float4 a = wv[c4], p = pv[c4];
            sum += a.x * p.x + a.y * p.y + a.z * p.z + a.w * p.w;
        }
        size_t oi = ((size_t)b * C_ + o) * C_ + h * CH_ + d;
        unsigned short hh = rne_bf16(sum);
        MTh[oi] = hh;
        MTl[oi] = rne_bf16(sum - bf16_f32(hh));
    }
}

extern "C" void kernel_launch(void* const* d_in, const int* in_sizes, int n_in,
                              void* d_out, int out_size, void* d_ws, size_t ws_size,
                              hipStream_t stream) {
    const float* x     = (const float*)d_in[0];
    const float* wqkv  = (const float*)d_in[1];
    const float* wdw   = (const float*)d_in[2];
    const float* wproj = (const float*)d_in[3];
    const float* temp  = (const float*)d_in[4];
    float* out = (float*)d_out;
    char* ws = (char*)d_ws;

    unsigned short* wqkvH = (unsigned short*)(ws + 0);          // 221184 B
    unsigned short* wqkvL = (unsigned short*)(ws + 221184);     // 221184 B
    unsigned short* MTh   = (unsigned short*)(ws + 442368);     // 294912 B
    unsigned short* MTl   = (unsigned short*)(ws + 737280);     // 294912 B
    float* Sred = (float*)(ws + 1032192);                       // 153600 B
    float* y1 = (float*)(ws + 1185792);                         // 50331648 B
    float* Sp = y1;                                             // aliases y1
    float* q  = (float*)(ws + 51517440);                        // 50331648 B
    float* k  = (float*)(ws + 101849088);                       // 50331648 B
    unsigned int* v = (unsigned int*)q;                          // packed v in q slab

    hipLaunchKernelGGL(k0_split, dim3(432), dim3(256), 0, stream,
                       wqkv, wqkvH, wqkvL, 576 * 192);
    // q
    hipLaunchKernelGGL(kg_mfma, dim3(64, 3, 4), dim3(256), 0, stream,
                       wqkvH, wqkvL, 0, x, y1);
    hipLaunchKernelGGL(k2_dwconv, dim3(64, 192, 4), dim3(256), 0, stream,
                       y1, wdw, q, (unsigned int*)nullptr, 0, 0);
    // k
    hipLaunchKernelGGL(kg_mfma, dim3(64, 3, 4), dim3(256), 0, stream,
                       wqkvH + 192 * 192, wqkvL + 192 * 192, 0, x, y1);
    hipLaunchKernelGGL(k2_dwconv, dim3(64, 192, 4), dim3(256), 0, stream,
                       y1, wdw, k, (unsigned int*)nullptr, 1, 0);
    // attention -> MT (split)
    hipLaunchKernelGGL(k3_qk, dim3(CHUNKS_, 4, 4), dim3(256), 0, stream, q, k, Sp);
    hipLaunchKernelGGL(k4a_reduce, dim3(150), dim3(256), 0, stream, Sp, Sred);
    hipLaunchKernelGGL(k4b_softmax, dim3(16), dim3(256), 0, stream,
                       Sred, wproj, temp, MTh, MTl);
    // v (packed, into q slab)
    hipLaunchKernelGGL(kg_mfma, dim3(64, 3, 4), dim3(256), 0, stream,
                       wqkvH + 2 * 192 * 192, wqkvL + 2 * 192 * 192, 0, x, y1);
    hipLaunchKernelGGL(k2_dwconv, dim3(64, 192, 4), dim3(256), 0, stream,
                       y1, wdw, (float*)nullptr, v, 2, 1);
    // out = M @ v
    hipLaunchKernelGGL(kg_mfma_p, dim3(64, 3, 4), dim3(256), 0, stream,
                       MTh, MTl, C_ * C_, v, out);
}

// Round 5
// 236.990 us; speedup vs baseline: 4.2633x; 1.5487x over previous
//
#include <hip/hip_runtime.h>
#include <hip/hip_bf16.h>
#include <math.h>

// Restormer-style channel attention. Round 5: k2_dwconv 4x4 register tile
// (MLP fix: 18 loads -> 16 outputs per thread, float4 vectorized).
// B=4, C=192, H=W=128, HEADS=4, ch=48, HW=16384.

#define B_ 4
#define C_ 192
#define H_ 128
#define W_ 128
#define HW_ 16384
#define HEADS_ 4
#define CH_ 48
#define CHUNKS_ 64

typedef __attribute__((ext_vector_type(8))) __bf16 bf16x8;
typedef __attribute__((ext_vector_type(8))) unsigned short u16x8;
typedef __attribute__((ext_vector_type(4))) float f32x4;

__device__ __forceinline__ unsigned short rne_bf16(float f) {
    unsigned int u = __float_as_uint(f);
    u += 0x7FFFu + ((u >> 16) & 1u);
    return (unsigned short)(u >> 16);
}
__device__ __forceinline__ float bf16_f32(unsigned short h) {
    return __uint_as_float(((unsigned int)h) << 16);
}

// split weights into bf16 hi/lo (RNE both)
__global__ void k0_split(const float* __restrict__ wq,
                         unsigned short* __restrict__ wH,
                         unsigned short* __restrict__ wL, int n) {
    int idx = blockIdx.x * 256 + threadIdx.x;
    if (idx < n) {
        float f = wq[idx];
        unsigned short h = rne_bf16(f);
        wH[idx] = h;
        wL[idx] = rne_bf16(f - bf16_f32(h));
    }
}

// ---------------- GEMM: Y[b][m][p] = sum_k A[m][k] * X[b][k][p] -------------
// f32-input variant (in-kernel trunc-hi/rne-lo split of X).
__global__ __launch_bounds__(256, 3) void kg_mfma(
    const unsigned short* __restrict__ Ah, const unsigned short* __restrict__ Al,
    int aStrideB, const float* __restrict__ X, float* __restrict__ Y) {
    __shared__ unsigned short AhL[64 * 40];
    __shared__ unsigned short AlL[64 * 40];
    __shared__ unsigned short BhL[256 * 40];
    __shared__ unsigned short BlL[256 * 40];
    int t = threadIdx.x;
    int wave = t >> 6, lane = t & 63;
    int lm = lane & 15, kg = lane >> 4;
    int p0 = blockIdx.x * 256;
    int m0 = blockIdx.y * 64;
    int b = blockIdx.z;
    const unsigned short* Abh = Ah + (size_t)b * aStrideB;
    const unsigned short* Abl = Al + (size_t)b * aStrideB;
    const float* Xb = X + (size_t)b * C_ * HW_ + p0 + t;

    f32x4 acc[4][4];
#pragma unroll
    for (int mi = 0; mi < 4; ++mi)
#pragma unroll
        for (int ni = 0; ni < 4; ++ni) acc[mi][ni] = (f32x4)(0.f);

    int ar = t >> 2, ac = (t & 3) * 8;

    for (int s = 0; s < 6; ++s) {
        int k0 = s * 32;
        __syncthreads();
        *(u16x8*)&AhL[ar * 40 + ac] =
            *(const u16x8*)&Abh[(size_t)(m0 + ar) * C_ + k0 + ac];
        *(u16x8*)&AlL[ar * 40 + ac] =
            *(const u16x8*)&Abl[(size_t)(m0 + ar) * C_ + k0 + ac];
#pragma unroll
        for (int half = 0; half < 2; ++half) {
            const float* xp = Xb + (size_t)(k0 + half * 16) * HW_;
            float xv[16];
#pragma unroll
            for (int i = 0; i < 16; ++i) xv[i] = xp[(size_t)i * HW_];
#pragma unroll
            for (int c8 = 0; c8 < 2; ++c8) {
                u16x8 hh, ll;
#pragma unroll
                for (int j = 0; j < 8; ++j) {
                    float f = xv[c8 * 8 + j];
                    unsigned int u = __float_as_uint(f);
                    hh[j] = (unsigned short)(u >> 16);  // trunc hi
                    float r = f - __uint_as_float(u & 0xFFFF0000u);
                    ll[j] = rne_bf16(r);
                }
                *(u16x8*)&BhL[t * 40 + half * 16 + c8 * 8] = hh;
                *(u16x8*)&BlL[t * 40 + half * 16 + c8 * 8] = ll;
            }
        }
        __syncthreads();
        bf16x8 fah[4], fal[4], fbh[4], fbl[4];
#pragma unroll
        for (int mi = 0; mi < 4; ++mi) {
            int ro = (lm + mi * 16) * 40 + kg * 8;
            fah[mi] = __builtin_bit_cast(bf16x8, *(const u16x8*)&AhL[ro]);
            fal[mi] = __builtin_bit_cast(bf16x8, *(const u16x8*)&AlL[ro]);
        }
#pragma unroll
        for (int ni = 0; ni < 4; ++ni) {
            int ro = (wave * 64 + ni * 16 + lm) * 40 + kg * 8;
            fbh[ni] = __builtin_bit_cast(bf16x8, *(const u16x8*)&BhL[ro]);
            fbl[ni] = __builtin_bit_cast(bf16x8, *(const u16x8*)&BlL[ro]);
        }
#pragma unroll
        for (int mi = 0; mi < 4; ++mi)
#pragma unroll
            for (int ni = 0; ni < 4; ++ni) {
                acc[mi][ni] = __builtin_amdgcn_mfma_f32_16x16x32_bf16(
                    fah[mi], fbh[ni], acc[mi][ni], 0, 0, 0);
                acc[mi][ni] = __builtin_amdgcn_mfma_f32_16x16x32_bf16(
                    fah[mi], fbl[ni], acc[mi][ni], 0, 0, 0);
                acc[mi][ni] = __builtin_amdgcn_mfma_f32_16x16x32_bf16(
                    fal[mi], fbh[ni], acc[mi][ni], 0, 0, 0);
            }
    }
#pragma unroll
    for (int mi = 0; mi < 4; ++mi)
#pragma unroll
        for (int ni = 0; ni < 4; ++ni) {
            int oc = m0 + mi * 16 + kg * 4;
            int px = p0 + wave * 64 + ni * 16 + lm;
            float* yp = Y + ((size_t)b * C_ + oc) * HW_ + px;
#pragma unroll
            for (int r = 0; r < 4; ++r) yp[(size_t)r * HW_] = acc[mi][ni][r];
        }
}

// packed-split-input variant (X = u32: lo16=hi-bf16, hi16=lo-bf16)
__global__ __launch_bounds__(256, 3) void kg_mfma_p(
    const unsigned short* __restrict__ Ah, const unsigned short* __restrict__ Al,
    int aStrideB, const unsigned int* __restrict__ X, float* __restrict__ Y) {
    __shared__ unsigned short AhL[64 * 40];
    __shared__ unsigned short AlL[64 * 40];
    __shared__ unsigned short BhL[256 * 40];
    __shared__ unsigned short BlL[256 * 40];
    int t = threadIdx.x;
    int wave = t >> 6, lane = t & 63;
    int lm = lane & 15, kg = lane >> 4;
    int p0 = blockIdx.x * 256;
    int m0 = blockIdx.y * 64;
    int b = blockIdx.z;
    const unsigned short* Abh = Ah + (size_t)b * aStrideB;
    const unsigned short* Abl = Al + (size_t)b * aStrideB;
    const unsigned int* Xb = X + (size_t)b * C_ * HW_ + p0 + t;

    f32x4 acc[4][4];
#pragma unroll
    for (int mi = 0; mi < 4; ++mi)
#pragma unroll
        for (int ni = 0; ni < 4; ++ni) acc[mi][ni] = (f32x4)(0.f);

    int ar = t >> 2, ac = (t & 3) * 8;

    for (int s = 0; s < 6; ++s) {
        int k0 = s * 32;
        __syncthreads();
        *(u16x8*)&AhL[ar * 40 + ac] =
            *(const u16x8*)&Abh[(size_t)(m0 + ar) * C_ + k0 + ac];
        *(u16x8*)&AlL[ar * 40 + ac] =
            *(const u16x8*)&Abl[(size_t)(m0 + ar) * C_ + k0 + ac];
#pragma unroll
        for (int half = 0; half < 2; ++half) {
            const unsigned int* xp = Xb + (size_t)(k0 + half * 16) * HW_;
            unsigned int xv[16];
#pragma unroll
            for (int i = 0; i < 16; ++i) xv[i] = xp[(size_t)i * HW_];
#pragma unroll
            for (int c8 = 0; c8 < 2; ++c8) {
                u16x8 hh, ll;
#pragma unroll
                for (int j = 0; j < 8; ++j) {
                    unsigned int u = xv[c8 * 8 + j];
                    hh[j] = (unsigned short)(u & 0xFFFFu);
                    ll[j] = (unsigned short)(u >> 16);
                }
                *(u16x8*)&BhL[t * 40 + half * 16 + c8 * 8] = hh;
                *(u16x8*)&BlL[t * 40 + half * 16 + c8 * 8] = ll;
            }
        }
        __syncthreads();
        bf16x8 fah[4], fal[4], fbh[4], fbl[4];
#pragma unroll
        for (int mi = 0; mi < 4; ++mi) {
            int ro = (lm + mi * 16) * 40 + kg * 8;
            fah[mi] = __builtin_bit_cast(bf16x8, *(const u16x8*)&AhL[ro]);
            fal[mi] = __builtin_bit_cast(bf16x8, *(const u16x8*)&AlL[ro]);
        }
#pragma unroll
        for (int ni = 0; ni < 4; ++ni) {
            int ro = (wave * 64 + ni * 16 + lm) * 40 + kg * 8;
            fbh[ni] = __builtin_bit_cast(bf16x8, *(const u16x8*)&BhL[ro]);
            fbl[ni] = __builtin_bit_cast(bf16x8, *(const u16x8*)&BlL[ro]);
        }
#pragma unroll
        for (int mi = 0; mi < 4; ++mi)
#pragma unroll
            for (int ni = 0; ni < 4; ++ni) {
                acc[mi][ni] = __builtin_amdgcn_mfma_f32_16x16x32_bf16(
                    fah[mi], fbh[ni], acc[mi][ni], 0, 0, 0);
                acc[mi][ni] = __builtin_amdgcn_mfma_f32_16x16x32_bf16(
                    fah[mi], fbl[ni], acc[mi][ni], 0, 0, 0);
                acc[mi][ni] = __builtin_amdgcn_mfma_f32_16x16x32_bf16(
                    fal[mi], fbh[ni], acc[mi][ni], 0, 0, 0);
            }
    }
#pragma unroll
    for (int mi = 0; mi < 4; ++mi)
#pragma unroll
        for (int ni = 0; ni < 4; ++ni) {
            int oc = m0 + mi * 16 + kg * 4;
            int px = p0 + wave * 64 + ni * 16 + lm;
            float* yp = Y + ((size_t)b * C_ + oc) * HW_ + px;
#pragma unroll
            for (int r = 0; r < 4; ++r) yp[(size_t)r * HW_] = acc[mi][ni][r];
        }
}

// depthwise 3x3, zero pad; 4x4 register tile per thread (18 loads/16 outputs).
// Block: 256 threads = 8 row-groups x 32 col-groups -> 32 rows x 128 cols.
// pack=1 -> emit packed split-bf16 (u32: lo16=trunc-hi, hi16=rne-lo).
__global__ __launch_bounds__(256, 6) void k2_dwconv(
    const float* __restrict__ y1, const float* __restrict__ wdw,
    float* __restrict__ dstF, unsigned int* __restrict__ dstP, int g, int pack) {
    int t = threadIdx.x;
    int c = blockIdx.y, b = blockIdx.z;
    int cg = (t & 31) * 4;                       // col base (16B aligned)
    int r0i = blockIdx.x * 32 + (t >> 5) * 4;    // first output row
    const float* yp = y1 + ((size_t)b * C_ + c) * HW_;
    const float* wd = wdw + (size_t)(g * C_ + c) * 9;  // uniform -> s_load
    float w0 = wd[0], w1 = wd[1], w2 = wd[2];
    float w3 = wd[3], w4 = wd[4], w5 = wd[5];
    float w6 = wd[6], w7 = wd[7], w8 = wd[8];
    bool lv = cg > 0, rv = cg < W_ - 4;

    float4 mid[6];
    float lf[6], rt[6];
#pragma unroll
    for (int i = 0; i < 6; ++i) {
        int rr = r0i - 1 + i;
        if (rr >= 0 && rr < H_) {
            const float* rowp = yp + (size_t)rr * W_;
            mid[i] = *(const float4*)&rowp[cg];
            lf[i] = lv ? rowp[cg - 1] : 0.f;
            rt[i] = rv ? rowp[cg + 4] : 0.f;
        } else {
            mid[i] = make_float4(0.f, 0.f, 0.f, 0.f);
            lf[i] = 0.f;
            rt[i] = 0.f;
        }
    }
#pragma unroll
    for (int i = 0; i < 4; ++i) {
        float o0 = 0.f, o1 = 0.f, o2 = 0.f, o3 = 0.f;
#pragma unroll
        for (int k = 0; k < 3; ++k) {
            float4 m = mid[i + k];
            float L = lf[i + k], R = rt[i + k];
            float wa = (k == 0) ? w0 : (k == 1) ? w3 : w6;
            float wb = (k == 0) ? w1 : (k == 1) ? w4 : w7;
            float wc = (k == 0) ? w2 : (k == 1) ? w5 : w8;
            o0 = fmaf(wa, L,   fmaf(wb, m.x, fmaf(wc, m.y, o0)));
            o1 = fmaf(wa, m.x, fmaf(wb, m.y, fmaf(wc, m.z, o1)));
            o2 = fmaf(wa, m.y, fmaf(wb, m.z, fmaf(wc, m.w, o2)));
            o3 = fmaf(wa, m.z, fmaf(wb, m.w, fmaf(wc, R,   o3)));
        }
        size_t oi = ((size_t)b * C_ + c) * HW_ + (size_t)(r0i + i) * W_ + cg;
        if (pack) {
            uint4 pk;
            float vals[4] = {o0, o1, o2, o3};
            unsigned int pks[4];
#pragma unroll
            for (int j = 0; j < 4; ++j) {
                unsigned int u = __float_as_uint(vals[j]);
                unsigned short h = (unsigned short)(u >> 16);  // trunc hi
                float r = vals[j] - __uint_as_float(u & 0xFFFF0000u);
                pks[j] = (unsigned int)h | ((unsigned int)rne_bf16(r) << 16);
            }
            pk.x = pks[0]; pk.y = pks[1]; pk.z = pks[2]; pk.w = pks[3];
            *(uint4*)&dstP[oi] = pk;
        } else {
            *(float4*)&dstF[oi] = make_float4(o0, o1, o2, o3);
        }
    }
}

// S-GEMM partials per (b,h,chunk of 256 px): S[48][48] + qss[48] + kss[48]
__global__ __launch_bounds__(256, 4) void k3_qk(
    const float* __restrict__ qb, const float* __restrict__ kb,
    float* __restrict__ Sp) {
    __shared__ float qs[48 * 66];
    __shared__ float ks[48 * 66];
    __shared__ float sredN[4 * 96];
    int t = threadIdx.x;
    int chunk = blockIdx.x, h = blockIdx.y, b = blockIdx.z;
    int w = t >> 6, l = t & 63;
    int ci = (l & 7) * 6, di = (l >> 3) * 6;
    const float* qrow = qb + ((size_t)b * C_ + h * CH_) * HW_;
    const float* krow = kb + ((size_t)b * C_ + h * CH_) * HW_;
    float S[6][6];
#pragma unroll
    for (int uc = 0; uc < 6; ++uc)
#pragma unroll
        for (int ud = 0; ud < 6; ++ud) S[uc][ud] = 0.f;
    float qss[6] = {0, 0, 0, 0, 0, 0}, kss[6] = {0, 0, 0, 0, 0, 0};

    for (int s = 0; s < 4; ++s) {
        __syncthreads();
        int base = chunk * 256 + s * 64;
        for (int idx = t; idx < 48 * 64; idx += 256) {
            int c = idx >> 6, j = idx & 63;
            qs[c * 66 + j] = qrow[(size_t)c * HW_ + base + j];
            ks[c * 66 + j] = krow[(size_t)c * HW_ + base + j];
        }
        __syncthreads();
        for (int jo = 0; jo < 16; ++jo) {
            int jj = w * 16 + jo;
            float rq[6], rk[6];
#pragma unroll
            for (int u = 0; u < 6; ++u) {
                rq[u] = qs[(ci + u) * 66 + jj];
                rk[u] = ks[(di + u) * 66 + jj];
            }
#pragma unroll
            for (int uc = 0; uc < 6; ++uc)
#pragma unroll
                for (int ud = 0; ud < 6; ++ud)
                    S[uc][ud] = fmaf(rq[uc], rk[ud], S[uc][ud]);
            if (l < 8) {
#pragma unroll
                for (int u = 0; u < 6; ++u) qss[u] = fmaf(rq[u], rq[u], qss[u]);
            }
            if ((l & 7) == 0) {
#pragma unroll
                for (int u = 0; u < 6; ++u) kss[u] = fmaf(rk[u], rk[u], kss[u]);
            }
        }
    }
    __syncthreads();
    float* red0 = qs;
    float* red1 = ks;
    if (w < 2) {
        float* r = (w == 0) ? red0 : red1;
#pragma unroll
        for (int uc = 0; uc < 6; ++uc)
#pragma unroll
            for (int ud = 0; ud < 6; ++ud)
                r[(ci + uc) * 48 + (di + ud)] = S[uc][ud];
    }
    if (l < 8) {
#pragma unroll
        for (int u = 0; u < 6; ++u) sredN[w * 96 + ci + u] = qss[u];
    }
    if ((l & 7) == 0) {
#pragma unroll
        for (int u = 0; u < 6; ++u) sredN[w * 96 + 48 + di + u] = kss[u];
    }
    __syncthreads();
    if (w >= 2) {
        float* r = (w == 2) ? red0 : red1;
#pragma unroll
        for (int uc = 0; uc < 6; ++uc)
#pragma unroll
            for (int ud = 0; ud < 6; ++ud)
                r[(ci + uc) * 48 + (di + ud)] += S[uc][ud];
    }
    __syncthreads();
    size_t ob = ((size_t)(b * HEADS_ + h) * CHUNKS_ + chunk) * 2400;
    for (int idx = t; idx < 2304; idx += 256)
        Sp[ob + idx] = red0[idx] + red1[idx];
    if (t < 96)
        Sp[ob + 2304 + t] = (sredN[t] + sredN[96 + t]) +
                            (sredN[192 + t] + sredN[288 + t]);
}

// parallel chunk-reduce: Sred[bh][0..2400) = sum over 64 chunk partials
__global__ __launch_bounds__(256, 8) void k4a_reduce(
    const float* __restrict__ Sp, float* __restrict__ Sred) {
    int idx = blockIdx.x * 256 + threadIdx.x;  // 38400 total
    if (idx >= 16 * 2400) return;
    int bh = idx / 2400, e = idx - bh * 2400;
    const float* p = Sp + (size_t)bh * CHUNKS_ * 2400 + e;
    float s = 0.f;
#pragma unroll 8
    for (int c = 0; c < CHUNKS_; ++c) s += p[(size_t)c * 2400];
    Sred[idx] = s;
}

// norms -> softmax (in-LDS) -> MT = wproj . blockdiag(attn), split-bf16 out
__global__ __launch_bounds__(256, 2) void k4b_softmax(
    const float* __restrict__ Sred, const float* __restrict__ wp,
    const float* __restrict__ temp,
    unsigned short* __restrict__ MTh, unsigned short* __restrict__ MTl) {
    __shared__ float sS[2304];       // scaled logits
    __shared__ float sT[2304];       // attn transposed [d][c]
    __shared__ float wpL[192 * 48];  // wproj head block [o][c]
    __shared__ float sNi[96];
    int t = threadIdx.x;
    int bh = blockIdx.x;
    int b = bh >> 2, h = bh & 3;
    const float* Sr = Sred + (size_t)bh * 2400;
    for (int idx = t; idx < 2304; idx += 256) sS[idx] = Sr[idx];
    if (t < 96) sNi[t] = 1.f / fmaxf(sqrtf(fmaxf(Sr[2304 + t], 0.f)), 1e-12f);
    for (int i = t; i < 192 * 48; i += 256) {
        int o = i / 48, c = i - o * 48;
        wpL[i] = wp[(size_t)o * C_ + h * CH_ + c];
    }
    __syncthreads();
    if (t < 48) {
        float rq = sNi[t] * temp[h];
        float m = -1e30f;
#pragma unroll
        for (int d = 0; d < 48; ++d) {
            float v = sS[t * 48 + d] * rq * sNi[48 + d];
            sS[t * 48 + d] = v;
            m = fmaxf(m, v);
        }
        float sum = 0.f;
#pragma unroll
        for (int d = 0; d < 48; ++d) {
            float e = expf(sS[t * 48 + d] - m);
            sT[d * 48 + t] = e;
            sum += e;
        }
        float inv = 1.f / sum;
#pragma unroll
        for (int d = 0; d < 48; ++d) sT[d * 48 + t] *= inv;
    }
    __syncthreads();
    for (int i = t; i < 48 * 192; i += 256) {
        int d = i / 192, o = i - d * 192;
        const float4* wv = (const float4*)&wpL[o * 48];
        const float4* pv = (const float4*)&sT[d * 48];
        float sum = 0.f;
#pragma unroll
        for (int c4 = 0; c4 < 12; ++c4) {
            float4 a = wv[c4], p = pv[c4];
            sum += a.x * p.x + a.y * p.y + a.z * p.z + a.w * p.w;
        }
        size_t oi = ((size_t)b * C_ + o) * C_ + h * CH_ + d;
        unsigned short hh = rne_bf16(sum);
        MTh[oi] = hh;
        MTl[oi] = rne_bf16(sum - bf16_f32(hh));
    }
}

extern "C" void kernel_launch(void* const* d_in, const int* in_sizes, int n_in,
                              void* d_out, int out_size, void* d_ws, size_t ws_size,
                              hipStream_t stream) {
    const float* x     = (const float*)d_in[0];
    const float* wqkv  = (const float*)d_in[1];
    const float* wdw   = (const float*)d_in[2];
    const float* wproj = (const float*)d_in[3];
    const float* temp  = (const float*)d_in[4];
    float* out = (float*)d_out;
    char* ws = (char*)d_ws;

    unsigned short* wqkvH = (unsigned short*)(ws + 0);          // 221184 B
    unsigned short* wqkvL = (unsigned short*)(ws + 221184);     // 221184 B
    unsigned short* MTh   = (unsigned short*)(ws + 442368);     // 294912 B
    unsigned short* MTl   = (unsigned short*)(ws + 737280);     // 294912 B
    float* Sred = (float*)(ws + 1032192);                       // 153600 B
    float* y1 = (float*)(ws + 1185792);                         // 50331648 B
    float* Sp = y1;                                             // aliases y1
    float* q  = (float*)(ws + 51517440);                        // 50331648 B
    float* k  = (float*)(ws + 101849088);                       // 50331648 B
    unsigned int* v = (unsigned int*)q;                          // packed v in q slab

    hipLaunchKernelGGL(k0_split, dim3(432), dim3(256), 0, stream,
                       wqkv, wqkvH, wqkvL, 576 * 192);
    // q
    hipLaunchKernelGGL(kg_mfma, dim3(64, 3, 4), dim3(256), 0, stream,
                       wqkvH, wqkvL, 0, x, y1);
    hipLaunchKernelGGL(k2_dwconv, dim3(4, 192, 4), dim3(256), 0, stream,
                       y1, wdw, q, (unsigned int*)nullptr, 0, 0);
    // k
    hipLaunchKernelGGL(kg_mfma, dim3(64, 3, 4), dim3(256), 0, stream,
                       wqkvH + 192 * 192, wqkvL + 192 * 192, 0, x, y1);
    hipLaunchKernelGGL(k2_dwconv, dim3(4, 192, 4), dim3(256), 0, stream,
                       y1, wdw, k, (unsigned int*)nullptr, 1, 0);
    // attention -> MT (split)
    hipLaunchKernelGGL(k3_qk, dim3(CHUNKS_, 4, 4), dim3(256), 0, stream, q, k, Sp);
    hipLaunchKernelGGL(k4a_reduce, dim3(150), dim3(256), 0, stream, Sp, Sred);
    hipLaunchKernelGGL(k4b_softmax, dim3(16), dim3(256), 0, stream,
                       Sred, wproj, temp, MTh, MTl);
    // v (packed, into q slab)
    hipLaunchKernelGGL(kg_mfma, dim3(64, 3, 4), dim3(256), 0, stream,
                       wqkvH + 2 * 192 * 192, wqkvL + 2 * 192 * 192, 0, x, y1);
    hipLaunchKernelGGL(k2_dwconv, dim3(4, 192, 4), dim3(256), 0, stream,
                       y1, wdw, (float*)nullptr, v, 2, 1);
    // out = M @ v
    hipLaunchKernelGGL(kg_mfma_p, dim3(64, 3, 4), dim3(256), 0, stream,
                       MTh, MTl, C_ * C_, v, out);
}

// Round 6
// 216.277 us; speedup vs baseline: 4.6716x; 1.0958x over previous
//
#include <hip/hip_runtime.h>
#include <hip/hip_bf16.h>
#include <math.h>

// Restormer-style channel attention. Round 6: k3 -> split-bf16 MFMA split-K
// GEMM; q/k norms folded into k2 (deterministic block partials).
// B=4, C=192, H=W=128, HEADS=4, ch=48, HW=16384.

#define B_ 4
#define C_ 192
#define H_ 128
#define W_ 128
#define HW_ 16384
#define HEADS_ 4
#define CH_ 48
#define CHUNKS_ 64

typedef __attribute__((ext_vector_type(8))) __bf16 bf16x8;
typedef __attribute__((ext_vector_type(8))) unsigned short u16x8;
typedef __attribute__((ext_vector_type(4))) float f32x4;

__device__ __forceinline__ unsigned short rne_bf16(float f) {
    unsigned int u = __float_as_uint(f);
    u += 0x7FFFu + ((u >> 16) & 1u);
    return (unsigned short)(u >> 16);
}
__device__ __forceinline__ float bf16_f32(unsigned short h) {
    return __uint_as_float(((unsigned int)h) << 16);
}

// split weights into bf16 hi/lo (RNE both)
__global__ void k0_split(const float* __restrict__ wq,
                         unsigned short* __restrict__ wH,
                         unsigned short* __restrict__ wL, int n) {
    int idx = blockIdx.x * 256 + threadIdx.x;
    if (idx < n) {
        float f = wq[idx];
        unsigned short h = rne_bf16(f);
        wH[idx] = h;
        wL[idx] = rne_bf16(f - bf16_f32(h));
    }
}

// ---------------- GEMM: Y[b][m][p] = sum_k A[m][k] * X[b][k][p] -------------
// f32-input variant (in-kernel trunc-hi/rne-lo split of X).
__global__ __launch_bounds__(256, 3) void kg_mfma(
    const unsigned short* __restrict__ Ah, const unsigned short* __restrict__ Al,
    int aStrideB, const float* __restrict__ X, float* __restrict__ Y) {
    __shared__ unsigned short AhL[64 * 40];
    __shared__ unsigned short AlL[64 * 40];
    __shared__ unsigned short BhL[256 * 40];
    __shared__ unsigned short BlL[256 * 40];
    int t = threadIdx.x;
    int wave = t >> 6, lane = t & 63;
    int lm = lane & 15, kg = lane >> 4;
    int p0 = blockIdx.x * 256;
    int m0 = blockIdx.y * 64;
    int b = blockIdx.z;
    const unsigned short* Abh = Ah + (size_t)b * aStrideB;
    const unsigned short* Abl = Al + (size_t)b * aStrideB;
    const float* Xb = X + (size_t)b * C_ * HW_ + p0 + t;

    f32x4 acc[4][4];
#pragma unroll
    for (int mi = 0; mi < 4; ++mi)
#pragma unroll
        for (int ni = 0; ni < 4; ++ni) acc[mi][ni] = (f32x4)(0.f);

    int ar = t >> 2, ac = (t & 3) * 8;

    for (int s = 0; s < 6; ++s) {
        int k0 = s * 32;
        __syncthreads();
        *(u16x8*)&AhL[ar * 40 + ac] =
            *(const u16x8*)&Abh[(size_t)(m0 + ar) * C_ + k0 + ac];
        *(u16x8*)&AlL[ar * 40 + ac] =
            *(const u16x8*)&Abl[(size_t)(m0 + ar) * C_ + k0 + ac];
#pragma unroll
        for (int half = 0; half < 2; ++half) {
            const float* xp = Xb + (size_t)(k0 + half * 16) * HW_;
            float xv[16];
#pragma unroll
            for (int i = 0; i < 16; ++i) xv[i] = xp[(size_t)i * HW_];
#pragma unroll
            for (int c8 = 0; c8 < 2; ++c8) {
                u16x8 hh, ll;
#pragma unroll
                for (int j = 0; j < 8; ++j) {
                    float f = xv[c8 * 8 + j];
                    unsigned int u = __float_as_uint(f);
                    hh[j] = (unsigned short)(u >> 16);  // trunc hi
                    float r = f - __uint_as_float(u & 0xFFFF0000u);
                    ll[j] = rne_bf16(r);
                }
                *(u16x8*)&BhL[t * 40 + half * 16 + c8 * 8] = hh;
                *(u16x8*)&BlL[t * 40 + half * 16 + c8 * 8] = ll;
            }
        }
        __syncthreads();
        bf16x8 fah[4], fal[4], fbh[4], fbl[4];
#pragma unroll
        for (int mi = 0; mi < 4; ++mi) {
            int ro = (lm + mi * 16) * 40 + kg * 8;
            fah[mi] = __builtin_bit_cast(bf16x8, *(const u16x8*)&AhL[ro]);
            fal[mi] = __builtin_bit_cast(bf16x8, *(const u16x8*)&AlL[ro]);
        }
#pragma unroll
        for (int ni = 0; ni < 4; ++ni) {
            int ro = (wave * 64 + ni * 16 + lm) * 40 + kg * 8;
            fbh[ni] = __builtin_bit_cast(bf16x8, *(const u16x8*)&BhL[ro]);
            fbl[ni] = __builtin_bit_cast(bf16x8, *(const u16x8*)&BlL[ro]);
        }
#pragma unroll
        for (int mi = 0; mi < 4; ++mi)
#pragma unroll
            for (int ni = 0; ni < 4; ++ni) {
                acc[mi][ni] = __builtin_amdgcn_mfma_f32_16x16x32_bf16(
                    fah[mi], fbh[ni], acc[mi][ni], 0, 0, 0);
                acc[mi][ni] = __builtin_amdgcn_mfma_f32_16x16x32_bf16(
                    fah[mi], fbl[ni], acc[mi][ni], 0, 0, 0);
                acc[mi][ni] = __builtin_amdgcn_mfma_f32_16x16x32_bf16(
                    fal[mi], fbh[ni], acc[mi][ni], 0, 0, 0);
            }
    }
#pragma unroll
    for (int mi = 0; mi < 4; ++mi)
#pragma unroll
        for (int ni = 0; ni < 4; ++ni) {
            int oc = m0 + mi * 16 + kg * 4;
            int px = p0 + wave * 64 + ni * 16 + lm;
            float* yp = Y + ((size_t)b * C_ + oc) * HW_ + px;
#pragma unroll
            for (int r = 0; r < 4; ++r) yp[(size_t)r * HW_] = acc[mi][ni][r];
        }
}

// packed-split-input variant (X = u32: lo16=hi-bf16, hi16=lo-bf16)
__global__ __launch_bounds__(256, 3) void kg_mfma_p(
    const unsigned short* __restrict__ Ah, const unsigned short* __restrict__ Al,
    int aStrideB, const unsigned int* __restrict__ X, float* __restrict__ Y) {
    __shared__ unsigned short AhL[64 * 40];
    __shared__ unsigned short AlL[64 * 40];
    __shared__ unsigned short BhL[256 * 40];
    __shared__ unsigned short BlL[256 * 40];
    int t = threadIdx.x;
    int wave = t >> 6, lane = t & 63;
    int lm = lane & 15, kg = lane >> 4;
    int p0 = blockIdx.x * 256;
    int m0 = blockIdx.y * 64;
    int b = blockIdx.z;
    const unsigned short* Abh = Ah + (size_t)b * aStrideB;
    const unsigned short* Abl = Al + (size_t)b * aStrideB;
    const unsigned int* Xb = X + (size_t)b * C_ * HW_ + p0 + t;

    f32x4 acc[4][4];
#pragma unroll
    for (int mi = 0; mi < 4; ++mi)
#pragma unroll
        for (int ni = 0; ni < 4; ++ni) acc[mi][ni] = (f32x4)(0.f);

    int ar = t >> 2, ac = (t & 3) * 8;

    for (int s = 0; s < 6; ++s) {
        int k0 = s * 32;
        __syncthreads();
        *(u16x8*)&AhL[ar * 40 + ac] =
            *(const u16x8*)&Abh[(size_t)(m0 + ar) * C_ + k0 + ac];
        *(u16x8*)&AlL[ar * 40 + ac] =
            *(const u16x8*)&Abl[(size_t)(m0 + ar) * C_ + k0 + ac];
#pragma unroll
        for (int half = 0; half < 2; ++half) {
            const unsigned int* xp = Xb + (size_t)(k0 + half * 16) * HW_;
            unsigned int xv[16];
#pragma unroll
            for (int i = 0; i < 16; ++i) xv[i] = xp[(size_t)i * HW_];
#pragma unroll
            for (int c8 = 0; c8 < 2; ++c8) {
                u16x8 hh, ll;
#pragma unroll
                for (int j = 0; j < 8; ++j) {
                    unsigned int u = xv[c8 * 8 + j];
                    hh[j] = (unsigned short)(u & 0xFFFFu);
                    ll[j] = (unsigned short)(u >> 16);
                }
                *(u16x8*)&BhL[t * 40 + half * 16 + c8 * 8] = hh;
                *(u16x8*)&BlL[t * 40 + half * 16 + c8 * 8] = ll;
            }
        }
        __syncthreads();
        bf16x8 fah[4], fal[4], fbh[4], fbl[4];
#pragma unroll
        for (int mi = 0; mi < 4; ++mi) {
            int ro = (lm + mi * 16) * 40 + kg * 8;
            fah[mi] = __builtin_bit_cast(bf16x8, *(const u16x8*)&AhL[ro]);
            fal[mi] = __builtin_bit_cast(bf16x8, *(const u16x8*)&AlL[ro]);
        }
#pragma unroll
        for (int ni = 0; ni < 4; ++ni) {
            int ro = (wave * 64 + ni * 16 + lm) * 40 + kg * 8;
            fbh[ni] = __builtin_bit_cast(bf16x8, *(const u16x8*)&BhL[ro]);
            fbl[ni] = __builtin_bit_cast(bf16x8, *(const u16x8*)&BlL[ro]);
        }
#pragma unroll
        for (int mi = 0; mi < 4; ++mi)
#pragma unroll
            for (int ni = 0; ni < 4; ++ni) {
                acc[mi][ni] = __builtin_amdgcn_mfma_f32_16x16x32_bf16(
                    fah[mi], fbh[ni], acc[mi][ni], 0, 0, 0);
                acc[mi][ni] = __builtin_amdgcn_mfma_f32_16x16x32_bf16(
                    fah[mi], fbl[ni], acc[mi][ni], 0, 0, 0);
                acc[mi][ni] = __builtin_amdgcn_mfma_f32_16x16x32_bf16(
                    fal[mi], fbh[ni], acc[mi][ni], 0, 0, 0);
            }
    }
#pragma unroll
    for (int mi = 0; mi < 4; ++mi)
#pragma unroll
        for (int ni = 0; ni < 4; ++ni) {
            int oc = m0 + mi * 16 + kg * 4;
            int px = p0 + wave * 64 + ni * 16 + lm;
            float* yp = Y + ((size_t)b * C_ + oc) * HW_ + px;
#pragma unroll
            for (int r = 0; r < 4; ++r) yp[(size_t)r * HW_] = acc[mi][ni][r];
        }
}

// depthwise 3x3, zero pad; 4x4 register tile per thread. Always emits packed
// split-bf16 (u32: lo16=trunc-hi, hi16=rne-lo). If ssP != nullptr, also emits
// deterministic per-block sum-of-squares partial: ssP[(b*C+c)*4 + rowblk].
__global__ __launch_bounds__(256, 6) void k2_dwconv(
    const float* __restrict__ y1, const float* __restrict__ wdw,
    unsigned int* __restrict__ dstP, float* __restrict__ ssP, int g) {
    __shared__ float wss[4];
    int t = threadIdx.x;
    int c = blockIdx.y, b = blockIdx.z;
    int cg = (t & 31) * 4;                       // col base (16B aligned)
    int r0i = blockIdx.x * 32 + (t >> 5) * 4;    // first output row
    const float* yp = y1 + ((size_t)b * C_ + c) * HW_;
    const float* wd = wdw + (size_t)(g * C_ + c) * 9;  // uniform -> s_load
    float w0 = wd[0], w1 = wd[1], w2 = wd[2];
    float w3 = wd[3], w4 = wd[4], w5 = wd[5];
    float w6 = wd[6], w7 = wd[7], w8 = wd[8];
    bool lv = cg > 0, rv = cg < W_ - 4;

    float4 mid[6];
    float lf[6], rt[6];
#pragma unroll
    for (int i = 0; i < 6; ++i) {
        int rr = r0i - 1 + i;
        if (rr >= 0 && rr < H_) {
            const float* rowp = yp + (size_t)rr * W_;
            mid[i] = *(const float4*)&rowp[cg];
            lf[i] = lv ? rowp[cg - 1] : 0.f;
            rt[i] = rv ? rowp[cg + 4] : 0.f;
        } else {
            mid[i] = make_float4(0.f, 0.f, 0.f, 0.f);
            lf[i] = 0.f;
            rt[i] = 0.f;
        }
    }
    float ss = 0.f;
#pragma unroll
    for (int i = 0; i < 4; ++i) {
        float o0 = 0.f, o1 = 0.f, o2 = 0.f, o3 = 0.f;
#pragma unroll
        for (int k = 0; k < 3; ++k) {
            float4 m = mid[i + k];
            float L = lf[i + k], R = rt[i + k];
            float wa = (k == 0) ? w0 : (k == 1) ? w3 : w6;
            float wb = (k == 0) ? w1 : (k == 1) ? w4 : w7;
            float wc = (k == 0) ? w2 : (k == 1) ? w5 : w8;
            o0 = fmaf(wa, L,   fmaf(wb, m.x, fmaf(wc, m.y, o0)));
            o1 = fmaf(wa, m.x, fmaf(wb, m.y, fmaf(wc, m.z, o1)));
            o2 = fmaf(wa, m.y, fmaf(wb, m.z, fmaf(wc, m.w, o2)));
            o3 = fmaf(wa, m.z, fmaf(wb, m.w, fmaf(wc, R,   o3)));
        }
        ss += o0 * o0 + o1 * o1 + o2 * o2 + o3 * o3;
        size_t oi = ((size_t)b * C_ + c) * HW_ + (size_t)(r0i + i) * W_ + cg;
        uint4 pk;
        float vals[4] = {o0, o1, o2, o3};
        unsigned int pks[4];
#pragma unroll
        for (int j = 0; j < 4; ++j) {
            unsigned int u = __float_as_uint(vals[j]);
            unsigned short h = (unsigned short)(u >> 16);  // trunc hi
            float r = vals[j] - __uint_as_float(u & 0xFFFF0000u);
            pks[j] = (unsigned int)h | ((unsigned int)rne_bf16(r) << 16);
        }
        pk.x = pks[0]; pk.y = pks[1]; pk.z = pks[2]; pk.w = pks[3];
        *(uint4*)&dstP[oi] = pk;
    }
    if (ssP != nullptr) {
#pragma unroll
        for (int m = 32; m >= 1; m >>= 1) ss += __shfl_xor(ss, m, 64);
        if ((t & 63) == 0) wss[t >> 6] = ss;
        __syncthreads();
        if (t == 0)
            ssP[((size_t)b * C_ + c) * 4 + blockIdx.x] =
                (wss[0] + wss[1]) + (wss[2] + wss[3]);
    }
}

// S-GEMM partials via split-bf16 MFMA. Per (b,h,chunk of 256 px):
// S[48][48] += q . k^T over the chunk; 4 waves split K (32 px each per stage),
// 2 stages of 128 px; fixed-order 4-wave LDS reduce -> Sp[bh][chunk][2304].
__global__ __launch_bounds__(256, 3) void k3_qk(
    const unsigned int* __restrict__ qp, const unsigned int* __restrict__ kp,
    float* __restrict__ Sp) {
    __shared__ unsigned int smem[12672];  // 50688 B; staging + (alias) reduce
    unsigned short* qh = (unsigned short*)smem;   // [48][132] u16
    unsigned short* ql = qh + 6336;
    unsigned short* kh = qh + 12672;
    unsigned short* kl = qh + 19008;
    float* red = (float*)smem;                    // 4*2304 floats (alias)
    int t = threadIdx.x;
    int w = t >> 6, lane = t & 63, lm = lane & 15, kg = lane >> 4;
    int chunk = blockIdx.x, h = blockIdx.y, b = blockIdx.z;
    const unsigned int* qb = qp + ((size_t)b * C_ + h * CH_) * HW_;
    const unsigned int* kb = kp + ((size_t)b * C_ + h * CH_) * HW_;

    f32x4 acc[3][3];
#pragma unroll
    for (int mi = 0; mi < 3; ++mi)
#pragma unroll
        for (int ni = 0; ni < 3; ++ni) acc[mi][ni] = (f32x4)(0.f);

    for (int s = 0; s < 2; ++s) {
        int base = chunk * 256 + s * 128;
        __syncthreads();
#pragma unroll
        for (int i = 0; i < 12; ++i) {
            int p = t + i * 256;          // 0..3071
            int c = p >> 6, jp = p & 63;  // row, px-pair
            uint2 qv = *(const uint2*)&qb[(size_t)c * HW_ + base + jp * 2];
            uint2 kv = *(const uint2*)&kb[(size_t)c * HW_ + base + jp * 2];
            int da = c * 66 + jp;         // dword index within each array
            ((unsigned int*)qh)[da] = (qv.x & 0xFFFFu) | (qv.y << 16);
            ((unsigned int*)ql)[da] = (qv.x >> 16) | (qv.y & 0xFFFF0000u);
            ((unsigned int*)kh)[da] = (kv.x & 0xFFFFu) | (kv.y << 16);
            ((unsigned int*)kl)[da] = (kv.x >> 16) | (kv.y & 0xFFFF0000u);
        }
        __syncthreads();
        bf16x8 fqh[3], fql[3], fkh[3], fkl[3];
#pragma unroll
        for (int mi = 0; mi < 3; ++mi) {
            int off = (lm + 16 * mi) * 132 + w * 32 + kg * 8;
            fqh[mi] = __builtin_bit_cast(bf16x8, *(const u16x8*)&qh[off]);
            fql[mi] = __builtin_bit_cast(bf16x8, *(const u16x8*)&ql[off]);
            fkh[mi] = __builtin_bit_cast(bf16x8, *(const u16x8*)&kh[off]);
            fkl[mi] = __builtin_bit_cast(bf16x8, *(const u16x8*)&kl[off]);
        }
#pragma unroll
        for (int mi = 0; mi < 3; ++mi)
#pragma unroll
            for (int ni = 0; ni < 3; ++ni) {
                acc[mi][ni] = __builtin_amdgcn_mfma_f32_16x16x32_bf16(
                    fqh[mi], fkh[ni], acc[mi][ni], 0, 0, 0);
                acc[mi][ni] = __builtin_amdgcn_mfma_f32_16x16x32_bf16(
                    fqh[mi], fkl[ni], acc[mi][ni], 0, 0, 0);
                acc[mi][ni] = __builtin_amdgcn_mfma_f32_16x16x32_bf16(
                    fql[mi], fkh[ni], acc[mi][ni], 0, 0, 0);
            }
    }
    __syncthreads();
#pragma unroll
    for (int mi = 0; mi < 3; ++mi)
#pragma unroll
        for (int ni = 0; ni < 3; ++ni) {
            int tile = mi * 3 + ni;
            *(f32x4*)&red[w * 2304 + tile * 256 + lane * 4] = acc[mi][ni];
        }
    __syncthreads();
    size_t ob = ((size_t)(b * HEADS_ + h) * CHUNKS_ + chunk) * 2304;
    for (int idx = t; idx < 2304; idx += 256) {
        float sv = (red[idx] + red[2304 + idx]) +
                   (red[4608 + idx] + red[6912 + idx]);
        int tile = idx >> 8, li = idx & 255;
        int ln = li >> 2, r = li & 3;
        int mi = tile / 3, ni = tile - mi * 3;
        int sidx = (mi * 16 + (ln >> 4) * 4 + r) * 48 + ni * 16 + (ln & 15);
        Sp[ob + sidx] = sv;
    }
}

// parallel chunk-reduce: Sred[bh][0..2304) = sum over 64 chunk partials
__global__ __launch_bounds__(256, 8) void k4a_reduce(
    const float* __restrict__ Sp, float* __restrict__ Sred) {
    int idx = blockIdx.x * 256 + threadIdx.x;  // 36864 total
    if (idx >= 16 * 2304) return;
    int bh = idx / 2304, e = idx - bh * 2304;
    const float* p = Sp + (size_t)bh * CHUNKS_ * 2304 + e;
    float s = 0.f;
#pragma unroll 8
    for (int c = 0; c < CHUNKS_; ++c) s += p[(size_t)c * 2304];
    Sred[idx] = s;
}

// norms (from k2 ss partials) -> softmax (in-LDS) -> MT = wproj.blockdiag(attn)
__global__ __launch_bounds__(256, 2) void k4b_softmax(
    const float* __restrict__ Sred, const float* __restrict__ ssPq,
    const float* __restrict__ ssPk, const float* __restrict__ wp,
    const float* __restrict__ temp,
    unsigned short* __restrict__ MTh, unsigned short* __restrict__ MTl) {
    __shared__ float sS[2304];       // scaled logits
    __shared__ float sT[2304];       // attn transposed [d][c]
    __shared__ float wpL[192 * 48];  // wproj head block [o][c]
    __shared__ float sNi[96];
    int t = threadIdx.x;
    int bh = blockIdx.x;
    int b = bh >> 2, h = bh & 3;
    const float* Sr = Sred + (size_t)bh * 2304;
    for (int idx = t; idx < 2304; idx += 256) sS[idx] = Sr[idx];
    if (t < 96) {
        int ch = h * CH_ + (t < 48 ? t : t - 48);
        const float* sp = (t < 48 ? ssPq : ssPk) + ((size_t)b * C_ + ch) * 4;
        float s4 = (sp[0] + sp[1]) + (sp[2] + sp[3]);
        sNi[t] = 1.f / fmaxf(sqrtf(fmaxf(s4, 0.f)), 1e-12f);
    }
    for (int i = t; i < 192 * 48; i += 256) {
        int o = i / 48, c = i - o * 48;
        wpL[i] = wp[(size_t)o * C_ + h * CH_ + c];
    }
    __syncthreads();
    if (t < 48) {
        float rq = sNi[t] * temp[h];
        float m = -1e30f;
#pragma unroll
        for (int d = 0; d < 48; ++d) {
            float v = sS[t * 48 + d] * rq * sNi[48 + d];
            sS[t * 48 + d] = v;
            m = fmaxf(m, v);
        }
        float sum = 0.f;
#pragma unroll
        for (int d = 0; d < 48; ++d) {
            float e = expf(sS[t * 48 + d] - m);
            sT[d * 48 + t] = e;
            sum += e;
        }
        float inv = 1.f / sum;
#pragma unroll
        for (int d = 0; d < 48; ++d) sT[d * 48 + t] *= inv;
    }
    __syncthreads();
    for (int i = t; i < 48 * 192; i += 256) {
        int d = i / 192, o = i - d * 192;
        const float4* wv = (const float4*)&wpL[o * 48];
        const float4* pv = (const float4*)&sT[d * 48];
        float sum = 0.f;
#pragma unroll
        for (int c4 = 0; c4 < 12; ++c4) {
            float4 a = wv[c4], p = pv[c4];
            sum += a.x * p.x + a.y * p.y + a.z * p.z + a.w * p.w;
        }
        size_t oi = ((size_t)b * C_ + o) * C_ + h * CH_ + d;
        unsigned short hh = rne_bf16(sum);
        MTh[oi] = hh;
        MTl[oi] = rne_bf16(sum - bf16_f32(hh));
    }
}

extern "C" void kernel_launch(void* const* d_in, const int* in_sizes, int n_in,
                              void* d_out, int out_size, void* d_ws, size_t ws_size,
                              hipStream_t stream) {
    const float* x     = (const float*)d_in[0];
    const float* wqkv  = (const float*)d_in[1];
    const float* wdw   = (const float*)d_in[2];
    const float* wproj = (const float*)d_in[3];
    const float* temp  = (const float*)d_in[4];
    float* out = (float*)d_out;
    char* ws = (char*)d_ws;

    unsigned short* wqkvH = (unsigned short*)(ws + 0);          // 221184 B
    unsigned short* wqkvL = (unsigned short*)(ws + 221184);     // 221184 B
    unsigned short* MTh   = (unsigned short*)(ws + 442368);     // 294912 B
    unsigned short* MTl   = (unsigned short*)(ws + 737280);     // 294912 B
    float* Sred = (float*)(ws + 1032192);                       // 147456 B
    float* ssPq = (float*)(ws + 1179648);                       // 12288 B
    float* ssPk = (float*)(ws + 1191936);                       // 12288 B
    float* y1 = (float*)(ws + 1204224);                         // 50331648 B
    float* Sp = y1;                                             // aliases y1
    unsigned int* q = (unsigned int*)(ws + 51535872);           // 50331648 B
    unsigned int* k = (unsigned int*)(ws + 101867520);          // 50331648 B
    unsigned int* v = q;                                        // v reuses q slab

    hipLaunchKernelGGL(k0_split, dim3(432), dim3(256), 0, stream,
                       wqkv, wqkvH, wqkvL, 576 * 192);
    // q
    hipLaunchKernelGGL(kg_mfma, dim3(64, 3, 4), dim3(256), 0, stream,
                       wqkvH, wqkvL, 0, x, y1);
    hipLaunchKernelGGL(k2_dwconv, dim3(4, 192, 4), dim3(256), 0, stream,
                       y1, wdw, q, ssPq, 0);
    // k
    hipLaunchKernelGGL(kg_mfma, dim3(64, 3, 4), dim3(256), 0, stream,
                       wqkvH + 192 * 192, wqkvL + 192 * 192, 0, x, y1);
    hipLaunchKernelGGL(k2_dwconv, dim3(4, 192, 4), dim3(256), 0, stream,
                       y1, wdw, k, ssPk, 1);
    // attention -> MT (split)
    hipLaunchKernelGGL(k3_qk, dim3(CHUNKS_, 4, 4), dim3(256), 0, stream, q, k, Sp);
    hipLaunchKernelGGL(k4a_reduce, dim3(144), dim3(256), 0, stream, Sp, Sred);
    hipLaunchKernelGGL(k4b_softmax, dim3(16), dim3(256), 0, stream,
                       Sred, ssPq, ssPk, wproj, temp, MTh, MTl);
    // v (packed, into q slab)
    hipLaunchKernelGGL(kg_mfma, dim3(64, 3, 4), dim3(256), 0, stream,
                       wqkvH + 2 * 192 * 192, wqkvL + 2 * 192 * 192, 0, x, y1);
    hipLaunchKernelGGL(k2_dwconv, dim3(4, 192, 4), dim3(256), 0, stream,
                       y1, wdw, v, (float*)nullptr, 2);
    // out = M @ v
    hipLaunchKernelGGL(kg_mfma_p, dim3(64, 3, 4), dim3(256), 0, stream,
                       MTh, MTl, C_ * C_, v, out);
}

// Round 7
// 212.387 us; speedup vs baseline: 4.7572x; 1.0183x over previous
//
#include <hip/hip_runtime.h>
#include <hip/hip_bf16.h>
#include <math.h>

// Restormer-style channel attention. Round 7: k4b bank-conflict fix
// (padded sS stride 49; wpL transposed [c][o] stride 196; float4-per-o reads).
// B=4, C=192, H=W=128, HEADS=4, ch=48, HW=16384.

#define B_ 4
#define C_ 192
#define H_ 128
#define W_ 128
#define HW_ 16384
#define HEADS_ 4
#define CH_ 48
#define CHUNKS_ 64

typedef __attribute__((ext_vector_type(8))) __bf16 bf16x8;
typedef __attribute__((ext_vector_type(8))) unsigned short u16x8;
typedef __attribute__((ext_vector_type(4))) float f32x4;

__device__ __forceinline__ unsigned short rne_bf16(float f) {
    unsigned int u = __float_as_uint(f);
    u += 0x7FFFu + ((u >> 16) & 1u);
    return (unsigned short)(u >> 16);
}
__device__ __forceinline__ float bf16_f32(unsigned short h) {
    return __uint_as_float(((unsigned int)h) << 16);
}

// split weights into bf16 hi/lo (RNE both)
__global__ void k0_split(const float* __restrict__ wq,
                         unsigned short* __restrict__ wH,
                         unsigned short* __restrict__ wL, int n) {
    int idx = blockIdx.x * 256 + threadIdx.x;
    if (idx < n) {
        float f = wq[idx];
        unsigned short h = rne_bf16(f);
        wH[idx] = h;
        wL[idx] = rne_bf16(f - bf16_f32(h));
    }
}

// ---------------- GEMM: Y[b][m][p] = sum_k A[m][k] * X[b][k][p] -------------
// f32-input variant (in-kernel trunc-hi/rne-lo split of X).
__global__ __launch_bounds__(256, 3) void kg_mfma(
    const unsigned short* __restrict__ Ah, const unsigned short* __restrict__ Al,
    int aStrideB, const float* __restrict__ X, float* __restrict__ Y) {
    __shared__ unsigned short AhL[64 * 40];
    __shared__ unsigned short AlL[64 * 40];
    __shared__ unsigned short BhL[256 * 40];
    __shared__ unsigned short BlL[256 * 40];
    int t = threadIdx.x;
    int wave = t >> 6, lane = t & 63;
    int lm = lane & 15, kg = lane >> 4;
    int p0 = blockIdx.x * 256;
    int m0 = blockIdx.y * 64;
    int b = blockIdx.z;
    const unsigned short* Abh = Ah + (size_t)b * aStrideB;
    const unsigned short* Abl = Al + (size_t)b * aStrideB;
    const float* Xb = X + (size_t)b * C_ * HW_ + p0 + t;

    f32x4 acc[4][4];
#pragma unroll
    for (int mi = 0; mi < 4; ++mi)
#pragma unroll
        for (int ni = 0; ni < 4; ++ni) acc[mi][ni] = (f32x4)(0.f);

    int ar = t >> 2, ac = (t & 3) * 8;

    for (int s = 0; s < 6; ++s) {
        int k0 = s * 32;
        __syncthreads();
        *(u16x8*)&AhL[ar * 40 + ac] =
            *(const u16x8*)&Abh[(size_t)(m0 + ar) * C_ + k0 + ac];
        *(u16x8*)&AlL[ar * 40 + ac] =
            *(const u16x8*)&Abl[(size_t)(m0 + ar) * C_ + k0 + ac];
#pragma unroll
        for (int half = 0; half < 2; ++half) {
            const float* xp = Xb + (size_t)(k0 + half * 16) * HW_;
            float xv[16];
#pragma unroll
            for (int i = 0; i < 16; ++i) xv[i] = xp[(size_t)i * HW_];
#pragma unroll
            for (int c8 = 0; c8 < 2; ++c8) {
                u16x8 hh, ll;
#pragma unroll
                for (int j = 0; j < 8; ++j) {
                    float f = xv[c8 * 8 + j];
                    unsigned int u = __float_as_uint(f);
                    hh[j] = (unsigned short)(u >> 16);  // trunc hi
                    float r = f - __uint_as_float(u & 0xFFFF0000u);
                    ll[j] = rne_bf16(r);
                }
                *(u16x8*)&BhL[t * 40 + half * 16 + c8 * 8] = hh;
                *(u16x8*)&BlL[t * 40 + half * 16 + c8 * 8] = ll;
            }
        }
        __syncthreads();
        bf16x8 fah[4], fal[4], fbh[4], fbl[4];
#pragma unroll
        for (int mi = 0; mi < 4; ++mi) {
            int ro = (lm + mi * 16) * 40 + kg * 8;
            fah[mi] = __builtin_bit_cast(bf16x8, *(const u16x8*)&AhL[ro]);
            fal[mi] = __builtin_bit_cast(bf16x8, *(const u16x8*)&AlL[ro]);
        }
#pragma unroll
        for (int ni = 0; ni < 4; ++ni) {
            int ro = (wave * 64 + ni * 16 + lm) * 40 + kg * 8;
            fbh[ni] = __builtin_bit_cast(bf16x8, *(const u16x8*)&BhL[ro]);
            fbl[ni] = __builtin_bit_cast(bf16x8, *(const u16x8*)&BlL[ro]);
        }
#pragma unroll
        for (int mi = 0; mi < 4; ++mi)
#pragma unroll
            for (int ni = 0; ni < 4; ++ni) {
                acc[mi][ni] = __builtin_amdgcn_mfma_f32_16x16x32_bf16(
                    fah[mi], fbh[ni], acc[mi][ni], 0, 0, 0);
                acc[mi][ni] = __builtin_amdgcn_mfma_f32_16x16x32_bf16(
                    fah[mi], fbl[ni], acc[mi][ni], 0, 0, 0);
                acc[mi][ni] = __builtin_amdgcn_mfma_f32_16x16x32_bf16(
                    fal[mi], fbh[ni], acc[mi][ni], 0, 0, 0);
            }
    }
#pragma unroll
    for (int mi = 0; mi < 4; ++mi)
#pragma unroll
        for (int ni = 0; ni < 4; ++ni) {
            int oc = m0 + mi * 16 + kg * 4;
            int px = p0 + wave * 64 + ni * 16 + lm;
            float* yp = Y + ((size_t)b * C_ + oc) * HW_ + px;
#pragma unroll
            for (int r = 0; r < 4; ++r) yp[(size_t)r * HW_] = acc[mi][ni][r];
        }
}

// packed-split-input variant (X = u32: lo16=hi-bf16, hi16=lo-bf16)
__global__ __launch_bounds__(256, 3) void kg_mfma_p(
    const unsigned short* __restrict__ Ah, const unsigned short* __restrict__ Al,
    int aStrideB, const unsigned int* __restrict__ X, float* __restrict__ Y) {
    __shared__ unsigned short AhL[64 * 40];
    __shared__ unsigned short AlL[64 * 40];
    __shared__ unsigned short BhL[256 * 40];
    __shared__ unsigned short BlL[256 * 40];
    int t = threadIdx.x;
    int wave = t >> 6, lane = t & 63;
    int lm = lane & 15, kg = lane >> 4;
    int p0 = blockIdx.x * 256;
    int m0 = blockIdx.y * 64;
    int b = blockIdx.z;
    const unsigned short* Abh = Ah + (size_t)b * aStrideB;
    const unsigned short* Abl = Al + (size_t)b * aStrideB;
    const unsigned int* Xb = X + (size_t)b * C_ * HW_ + p0 + t;

    f32x4 acc[4][4];
#pragma unroll
    for (int mi = 0; mi < 4; ++mi)
#pragma unroll
        for (int ni = 0; ni < 4; ++ni) acc[mi][ni] = (f32x4)(0.f);

    int ar = t >> 2, ac = (t & 3) * 8;

    for (int s = 0; s < 6; ++s) {
        int k0 = s * 32;
        __syncthreads();
        *(u16x8*)&AhL[ar * 40 + ac] =
            *(const u16x8*)&Abh[(size_t)(m0 + ar) * C_ + k0 + ac];
        *(u16x8*)&AlL[ar * 40 + ac] =
            *(const u16x8*)&Abl[(size_t)(m0 + ar) * C_ + k0 + ac];
#pragma unroll
        for (int half = 0; half < 2; ++half) {
            const unsigned int* xp = Xb + (size_t)(k0 + half * 16) * HW_;
            unsigned int xv[16];
#pragma unroll
            for (int i = 0; i < 16; ++i) xv[i] = xp[(size_t)i * HW_];
#pragma unroll
            for (int c8 = 0; c8 < 2; ++c8) {
                u16x8 hh, ll;
#pragma unroll
                for (int j = 0; j < 8; ++j) {
                    unsigned int u = xv[c8 * 8 + j];
                    hh[j] = (unsigned short)(u & 0xFFFFu);
                    ll[j] = (unsigned short)(u >> 16);
                }
                *(u16x8*)&BhL[t * 40 + half * 16 + c8 * 8] = hh;
                *(u16x8*)&BlL[t * 40 + half * 16 + c8 * 8] = ll;
            }
        }
        __syncthreads();
        bf16x8 fah[4], fal[4], fbh[4], fbl[4];
#pragma unroll
        for (int mi = 0; mi < 4; ++mi) {
            int ro = (lm + mi * 16) * 40 + kg * 8;
            fah[mi] = __builtin_bit_cast(bf16x8, *(const u16x8*)&AhL[ro]);
            fal[mi] = __builtin_bit_cast(bf16x8, *(const u16x8*)&AlL[ro]);
        }
#pragma unroll
        for (int ni = 0; ni < 4; ++ni) {
            int ro = (wave * 64 + ni * 16 + lm) * 40 + kg * 8;
            fbh[ni] = __builtin_bit_cast(bf16x8, *(const u16x8*)&BhL[ro]);
            fbl[ni] = __builtin_bit_cast(bf16x8, *(const u16x8*)&BlL[ro]);
        }
#pragma unroll
        for (int mi = 0; mi < 4; ++mi)
#pragma unroll
            for (int ni = 0; ni < 4; ++ni) {
                acc[mi][ni] = __builtin_amdgcn_mfma_f32_16x16x32_bf16(
                    fah[mi], fbh[ni], acc[mi][ni], 0, 0, 0);
                acc[mi][ni] = __builtin_amdgcn_mfma_f32_16x16x32_bf16(
                    fah[mi], fbl[ni], acc[mi][ni], 0, 0, 0);
                acc[mi][ni] = __builtin_amdgcn_mfma_f32_16x16x32_bf16(
                    fal[mi], fbh[ni], acc[mi][ni], 0, 0, 0);
            }
    }
#pragma unroll
    for (int mi = 0; mi < 4; ++mi)
#pragma unroll
        for (int ni = 0; ni < 4; ++ni) {
            int oc = m0 + mi * 16 + kg * 4;
            int px = p0 + wave * 64 + ni * 16 + lm;
            float* yp = Y + ((size_t)b * C_ + oc) * HW_ + px;
#pragma unroll
            for (int r = 0; r < 4; ++r) yp[(size_t)r * HW_] = acc[mi][ni][r];
        }
}

// depthwise 3x3, zero pad; 4x4 register tile per thread. Always emits packed
// split-bf16 (u32: lo16=trunc-hi, hi16=rne-lo). If ssP != nullptr, also emits
// deterministic per-block sum-of-squares partial: ssP[(b*C+c)*4 + rowblk].
__global__ __launch_bounds__(256, 6) void k2_dwconv(
    const float* __restrict__ y1, const float* __restrict__ wdw,
    unsigned int* __restrict__ dstP, float* __restrict__ ssP, int g) {
    __shared__ float wss[4];
    int t = threadIdx.x;
    int c = blockIdx.y, b = blockIdx.z;
    int cg = (t & 31) * 4;                       // col base (16B aligned)
    int r0i = blockIdx.x * 32 + (t >> 5) * 4;    // first output row
    const float* yp = y1 + ((size_t)b * C_ + c) * HW_;
    const float* wd = wdw + (size_t)(g * C_ + c) * 9;  // uniform -> s_load
    float w0 = wd[0], w1 = wd[1], w2 = wd[2];
    float w3 = wd[3], w4 = wd[4], w5 = wd[5];
    float w6 = wd[6], w7 = wd[7], w8 = wd[8];
    bool lv = cg > 0, rv = cg < W_ - 4;

    float4 mid[6];
    float lf[6], rt[6];
#pragma unroll
    for (int i = 0; i < 6; ++i) {
        int rr = r0i - 1 + i;
        if (rr >= 0 && rr < H_) {
            const float* rowp = yp + (size_t)rr * W_;
            mid[i] = *(const float4*)&rowp[cg];
            lf[i] = lv ? rowp[cg - 1] : 0.f;
            rt[i] = rv ? rowp[cg + 4] : 0.f;
        } else {
            mid[i] = make_float4(0.f, 0.f, 0.f, 0.f);
            lf[i] = 0.f;
            rt[i] = 0.f;
        }
    }
    float ss = 0.f;
#pragma unroll
    for (int i = 0; i < 4; ++i) {
        float o0 = 0.f, o1 = 0.f, o2 = 0.f, o3 = 0.f;
#pragma unroll
        for (int k = 0; k < 3; ++k) {
            float4 m = mid[i + k];
            float L = lf[i + k], R = rt[i + k];
            float wa = (k == 0) ? w0 : (k == 1) ? w3 : w6;
            float wb = (k == 0) ? w1 : (k == 1) ? w4 : w7;
            float wc = (k == 0) ? w2 : (k == 1) ? w5 : w8;
            o0 = fmaf(wa, L,   fmaf(wb, m.x, fmaf(wc, m.y, o0)));
            o1 = fmaf(wa, m.x, fmaf(wb, m.y, fmaf(wc, m.z, o1)));
            o2 = fmaf(wa, m.y, fmaf(wb, m.z, fmaf(wc, m.w, o2)));
            o3 = fmaf(wa, m.z, fmaf(wb, m.w, fmaf(wc, R,   o3)));
        }
        ss += o0 * o0 + o1 * o1 + o2 * o2 + o3 * o3;
        size_t oi = ((size_t)b * C_ + c) * HW_ + (size_t)(r0i + i) * W_ + cg;
        uint4 pk;
        float vals[4] = {o0, o1, o2, o3};
        unsigned int pks[4];
#pragma unroll
        for (int j = 0; j < 4; ++j) {
            unsigned int u = __float_as_uint(vals[j]);
            unsigned short h = (unsigned short)(u >> 16);  // trunc hi
            float r = vals[j] - __uint_as_float(u & 0xFFFF0000u);
            pks[j] = (unsigned int)h | ((unsigned int)rne_bf16(r) << 16);
        }
        pk.x = pks[0]; pk.y = pks[1]; pk.z = pks[2]; pk.w = pks[3];
        *(uint4*)&dstP[oi] = pk;
    }
    if (ssP != nullptr) {
#pragma unroll
        for (int m = 32; m >= 1; m >>= 1) ss += __shfl_xor(ss, m, 64);
        if ((t & 63) == 0) wss[t >> 6] = ss;
        __syncthreads();
        if (t == 0)
            ssP[((size_t)b * C_ + c) * 4 + blockIdx.x] =
                (wss[0] + wss[1]) + (wss[2] + wss[3]);
    }
}

// S-GEMM partials via split-bf16 MFMA. Per (b,h,chunk of 256 px):
// S[48][48] += q . k^T over the chunk; 4 waves split K (32 px each per stage),
// 2 stages of 128 px; fixed-order 4-wave LDS reduce -> Sp[bh][chunk][2304].
__global__ __launch_bounds__(256, 3) void k3_qk(
    const unsigned int* __restrict__ qp, const unsigned int* __restrict__ kp,
    float* __restrict__ Sp) {
    __shared__ unsigned int smem[12672];  // 50688 B; staging + (alias) reduce
    unsigned short* qh = (unsigned short*)smem;   // [48][132] u16
    unsigned short* ql = qh + 6336;
    unsigned short* kh = qh + 12672;
    unsigned short* kl = qh + 19008;
    float* red = (float*)smem;                    // 4*2304 floats (alias)
    int t = threadIdx.x;
    int w = t >> 6, lane = t & 63, lm = lane & 15, kg = lane >> 4;
    int chunk = blockIdx.x, h = blockIdx.y, b = blockIdx.z;
    const unsigned int* qb = qp + ((size_t)b * C_ + h * CH_) * HW_;
    const unsigned int* kb = kp + ((size_t)b * C_ + h * CH_) * HW_;

    f32x4 acc[3][3];
#pragma unroll
    for (int mi = 0; mi < 3; ++mi)
#pragma unroll
        for (int ni = 0; ni < 3; ++ni) acc[mi][ni] = (f32x4)(0.f);

    for (int s = 0; s < 2; ++s) {
        int base = chunk * 256 + s * 128;
        __syncthreads();
#pragma unroll
        for (int i = 0; i < 12; ++i) {
            int p = t + i * 256;          // 0..3071
            int c = p >> 6, jp = p & 63;  // row, px-pair
            uint2 qv = *(const uint2*)&qb[(size_t)c * HW_ + base + jp * 2];
            uint2 kv = *(const uint2*)&kb[(size_t)c * HW_ + base + jp * 2];
            int da = c * 66 + jp;         // dword index within each array
            ((unsigned int*)qh)[da] = (qv.x & 0xFFFFu) | (qv.y << 16);
            ((unsigned int*)ql)[da] = (qv.x >> 16) | (qv.y & 0xFFFF0000u);
            ((unsigned int*)kh)[da] = (kv.x & 0xFFFFu) | (kv.y << 16);
            ((unsigned int*)kl)[da] = (kv.x >> 16) | (kv.y & 0xFFFF0000u);
        }
        __syncthreads();
        bf16x8 fqh[3], fql[3], fkh[3], fkl[3];
#pragma unroll
        for (int mi = 0; mi < 3; ++mi) {
            int off = (lm + 16 * mi) * 132 + w * 32 + kg * 8;
            fqh[mi] = __builtin_bit_cast(bf16x8, *(const u16x8*)&qh[off]);
            fql[mi] = __builtin_bit_cast(bf16x8, *(const u16x8*)&ql[off]);
            fkh[mi] = __builtin_bit_cast(bf16x8, *(const u16x8*)&kh[off]);
            fkl[mi] = __builtin_bit_cast(bf16x8, *(const u16x8*)&kl[off]);
        }
#pragma unroll
        for (int mi = 0; mi < 3; ++mi)
#pragma unroll
            for (int ni = 0; ni < 3; ++ni) {
                acc[mi][ni] = __builtin_amdgcn_mfma_f32_16x16x32_bf16(
                    fqh[mi], fkh[ni], acc[mi][ni], 0, 0, 0);
                acc[mi][ni] = __builtin_amdgcn_mfma_f32_16x16x32_bf16(
                    fqh[mi], fkl[ni], acc[mi][ni], 0, 0, 0);
                acc[mi][ni] = __builtin_amdgcn_mfma_f32_16x16x32_bf16(
                    fql[mi], fkh[ni], acc[mi][ni], 0, 0, 0);
            }
    }
    __syncthreads();
#pragma unroll
    for (int mi = 0; mi < 3; ++mi)
#pragma unroll
        for (int ni = 0; ni < 3; ++ni) {
            int tile = mi * 3 + ni;
            *(f32x4*)&red[w * 2304 + tile * 256 + lane * 4] = acc[mi][ni];
        }
    __syncthreads();
    size_t ob = ((size_t)(b * HEADS_ + h) * CHUNKS_ + chunk) * 2304;
    for (int idx = t; idx < 2304; idx += 256) {
        float sv = (red[idx] + red[2304 + idx]) +
                   (red[4608 + idx] + red[6912 + idx]);
        int tile = idx >> 8, li = idx & 255;
        int ln = li >> 2, r = li & 3;
        int mi = tile / 3, ni = tile - mi * 3;
        int sidx = (mi * 16 + (ln >> 4) * 4 + r) * 48 + ni * 16 + (ln & 15);
        Sp[ob + sidx] = sv;
    }
}

// parallel chunk-reduce: Sred[bh][0..2304) = sum over 64 chunk partials
__global__ __launch_bounds__(256, 8) void k4a_reduce(
    const float* __restrict__ Sp, float* __restrict__ Sred) {
    int idx = blockIdx.x * 256 + threadIdx.x;  // 36864 total
    if (idx >= 16 * 2304) return;
    int bh = idx / 2304, e = idx - bh * 2304;
    const float* p = Sp + (size_t)bh * CHUNKS_ * 2304 + e;
    float s = 0.f;
#pragma unroll 8
    for (int c = 0; c < CHUNKS_; ++c) s += p[(size_t)c * 2304];
    Sred[idx] = s;
}

// norms (from k2 ss partials) -> softmax (in-LDS) -> MT = wproj.blockdiag(attn)
// Bank-conflict-free layouts: sS stride 49 (odd); wpL transposed [c][o] stride
// 196 (16B-aligned rows); MT loop: thread owns 4 consecutive o -> ideal b128.
__global__ __launch_bounds__(256, 2) void k4b_softmax(
    const float* __restrict__ Sred, const float* __restrict__ ssPq,
    const float* __restrict__ ssPk, const float* __restrict__ wp,
    const float* __restrict__ temp,
    unsigned short* __restrict__ MTh, unsigned short* __restrict__ MTl) {
    __shared__ float sS[48 * 49];     // logits [c][d], stride 49
    __shared__ float sT[48 * 48];     // probs transposed [d][c]
    __shared__ float wpL[48 * 196];   // wproj [c][o], stride 196
    __shared__ float sNi[96];
    int t = threadIdx.x;
    int bh = blockIdx.x;
    int b = bh >> 2, h = bh & 3;
    const float* Sr = Sred + (size_t)bh * 2304;
    for (int idx = t; idx < 2304; idx += 256) {
        int c = idx / 48, d = idx - c * 48;
        sS[c * 49 + d] = Sr[idx];
    }
    if (t < 96) {
        int ch = h * CH_ + (t < 48 ? t : t - 48);
        const float* sp = (t < 48 ? ssPq : ssPk) + ((size_t)b * C_ + ch) * 4;
        float s4 = (sp[0] + sp[1]) + (sp[2] + sp[3]);
        sNi[t] = 1.f / fmaxf(sqrtf(fmaxf(s4, 0.f)), 1e-12f);
    }
    for (int i = t; i < 192 * 48; i += 256) {
        int o = i / 48, c = i - o * 48;  // consecutive c -> coalesced global
        wpL[c * 196 + o] = wp[(size_t)o * C_ + h * CH_ + c];
    }
    __syncthreads();
    if (t < 48) {
        float rq = sNi[t] * temp[h];
        float m = -1e30f;
#pragma unroll
        for (int d = 0; d < 48; ++d) {
            float v = sS[t * 49 + d] * rq * sNi[48 + d];
            sS[t * 49 + d] = v;
            m = fmaxf(m, v);
        }
        float sum = 0.f;
#pragma unroll
        for (int d = 0; d < 48; ++d) {
            float e = expf(sS[t * 49 + d] - m);
            sT[d * 48 + t] = e;
            sum += e;
        }
        float inv = 1.f / sum;
#pragma unroll
        for (int d = 0; d < 48; ++d) sT[d * 48 + t] *= inv;
    }
    __syncthreads();
    // MT[d-col per head][4 o's per thread]: 48*48 (d, o-group) work items
    for (int i = t; i < 48 * 48; i += 256) {
        int d = i / 48, og = i - d * 48;
        float4 a = make_float4(0.f, 0.f, 0.f, 0.f);
#pragma unroll
        for (int c = 0; c < 48; ++c) {
            float4 wv = *(const float4*)&wpL[c * 196 + og * 4];  // 16B/lane
            float p = sT[d * 48 + c];                            // broadcast
            a.x = fmaf(wv.x, p, a.x);
            a.y = fmaf(wv.y, p, a.y);
            a.z = fmaf(wv.z, p, a.z);
            a.w = fmaf(wv.w, p, a.w);
        }
        float vals[4] = {a.x, a.y, a.z, a.w};
#pragma unroll
        for (int j = 0; j < 4; ++j) {
            size_t oi = ((size_t)b * C_ + og * 4 + j) * C_ + h * CH_ + d;
            unsigned short hh = rne_bf16(vals[j]);
            MTh[oi] = hh;
            MTl[oi] = rne_bf16(vals[j] - bf16_f32(hh));
        }
    }
}

extern "C" void kernel_launch(void* const* d_in, const int* in_sizes, int n_in,
                              void* d_out, int out_size, void* d_ws, size_t ws_size,
                              hipStream_t stream) {
    const float* x     = (const float*)d_in[0];
    const float* wqkv  = (const float*)d_in[1];
    const float* wdw   = (const float*)d_in[2];
    const float* wproj = (const float*)d_in[3];
    const float* temp  = (const float*)d_in[4];
    float* out = (float*)d_out;
    char* ws = (char*)d_ws;

    unsigned short* wqkvH = (unsigned short*)(ws + 0);          // 221184 B
    unsigned short* wqkvL = (unsigned short*)(ws + 221184);     // 221184 B
    unsigned short* MTh   = (unsigned short*)(ws + 442368);     // 294912 B
    unsigned short* MTl   = (unsigned short*)(ws + 737280);     // 294912 B
    float* Sred = (float*)(ws + 1032192);                       // 147456 B
    float* ssPq = (float*)(ws + 1179648);                       // 12288 B
    float* ssPk = (float*)(ws + 1191936);                       // 12288 B
    float* y1 = (float*)(ws + 1204224);                         // 50331648 B
    float* Sp = y1;                                             // aliases y1
    unsigned int* q = (unsigned int*)(ws + 51535872);           // 50331648 B
    unsigned int* k = (unsigned int*)(ws + 101867520);          // 50331648 B
    unsigned int* v = q;                                        // v reuses q slab

    hipLaunchKernelGGL(k0_split, dim3(432), dim3(256), 0, stream,
                       wqkv, wqkvH, wqkvL, 576 * 192);
    // q
    hipLaunchKernelGGL(kg_mfma, dim3(64, 3, 4), dim3(256), 0, stream,
                       wqkvH, wqkvL, 0, x, y1);
    hipLaunchKernelGGL(k2_dwconv, dim3(4, 192, 4), dim3(256), 0, stream,
                       y1, wdw, q, ssPq, 0);
    // k
    hipLaunchKernelGGL(kg_mfma, dim3(64, 3, 4), dim3(256), 0, stream,
                       wqkvH + 192 * 192, wqkvL + 192 * 192, 0, x, y1);
    hipLaunchKernelGGL(k2_dwconv, dim3(4, 192, 4), dim3(256), 0, stream,
                       y1, wdw, k, ssPk, 1);
    // attention -> MT (split)
    hipLaunchKernelGGL(k3_qk, dim3(CHUNKS_, 4, 4), dim3(256), 0, stream, q, k, Sp);
    hipLaunchKernelGGL(k4a_reduce, dim3(144), dim3(256), 0, stream, Sp, Sred);
    hipLaunchKernelGGL(k4b_softmax, dim3(16), dim3(256), 0, stream,
                       Sred, ssPq, ssPk, wproj, temp, MTh, MTl);
    // v (packed, into q slab)
    hipLaunchKernelGGL(kg_mfma, dim3(64, 3, 4), dim3(256), 0, stream,
                       wqkvH + 2 * 192 * 192, wqkvL + 2 * 192 * 192, 0, x, y1);
    hipLaunchKernelGGL(k2_dwconv, dim3(4, 192, 4), dim3(256), 0, stream,
                       y1, wdw, v, (float*)nullptr, 2);
    // out = M @ v
    hipLaunchKernelGGL(kg_mfma_p, dim3(64, 3, 4), dim3(256), 0, stream,
                       MTh, MTl, C_ * C_, v, out);
}